// Round 2
// baseline (3119.148 us; speedup 1.0000x reference)
//
#include <hip/hip_runtime.h>
#include <hip/hip_bf16.h>
#include <math.h>

#define EPS_BN 1e-5f

// ============================================================================
// conv1 + bias + BN + ReLU + maxpool2:  x[CH,1,48,48] -> out1 NHWC [CH,24,24,256]
// One block per image; thread = output channel. Input image staged zero-padded
// in LDS (all-thread broadcast reads). Stores coalesced (consecutive oc).
// ============================================================================
__global__ __launch_bounds__(256) void k_conv1(
    const float* __restrict__ x, const float* __restrict__ w,
    const float* __restrict__ cb, const float* __restrict__ g,
    const float* __restrict__ bb, const float* __restrict__ m,
    const float* __restrict__ v, float* __restrict__ out1) {
  __shared__ float xp[50 * 50];
  const int b = blockIdx.x;
  const int t = threadIdx.x;
  for (int i = t; i < 2500; i += 256) xp[i] = 0.f;
  __syncthreads();
  const float* xb = x + (size_t)b * 2304;
  for (int i = t; i < 2304; i += 256) {
    int r = i / 48, c = i - r * 48;
    xp[(r + 1) * 50 + (c + 1)] = xb[i];
  }
  __syncthreads();
  float wr[9];
#pragma unroll
  for (int i = 0; i < 9; i++) wr[i] = w[t * 9 + i];
  const float scale = g[t] * rsqrtf(v[t] + EPS_BN);
  const float bias = (cb[t] - m[t]) * scale + bb[t];
  float* ob = out1 + (size_t)b * (24 * 24 * 256);
  for (int oh = 0; oh < 24; oh++) {
    for (int ow = 0; ow < 24; ow++) {
      float p[4][4];
#pragma unroll
      for (int r = 0; r < 4; r++)
#pragma unroll
        for (int c = 0; c < 4; c++)
          p[r][c] = xp[(2 * oh + r) * 50 + (2 * ow + c)];
      float s4[4];
      int ii = 0;
#pragma unroll
      for (int dh = 0; dh < 2; dh++)
#pragma unroll
        for (int dw = 0; dw < 2; dw++, ii++) {
          float s = 0.f;
#pragma unroll
          for (int kh = 0; kh < 3; kh++)
#pragma unroll
            for (int kw = 0; kw < 3; kw++)
              s = fmaf(p[dh + kh][dw + kw], wr[kh * 3 + kw], s);
          s4[ii] = s * scale + bias;  // BN before pool (scale may be negative)
        }
      float mx = fmaxf(fmaxf(s4[0], s4[1]), fmaxf(s4[2], s4[3]));
      ob[(oh * 24 + ow) * 256 + t] = fmaxf(mx, 0.f);  // relu∘max == max∘relu
    }
  }
}

// ============================================================================
// Weight transposes: conv w [OC][IC][3][3] -> [9][IC][OC] (coalesced B tiles)
// ============================================================================
__global__ void k_tw2(const float* __restrict__ w, float* __restrict__ wt) {
  int idx = blockIdx.x * 256 + threadIdx.x;
  if (idx >= 9 * 256 * 128) return;
  int oc = idx & 127, ic = (idx >> 7) & 255, p = idx >> 15;
  wt[idx] = w[(oc * 256 + ic) * 9 + p];
}
__global__ void k_tw3(const float* __restrict__ w, float* __restrict__ wt) {
  int idx = blockIdx.x * 256 + threadIdx.x;
  if (idx >= 9 * 128 * 64) return;
  int oc = idx & 63, ic = (idx >> 6) & 127, p = idx >> 13;
  wt[idx] = w[(oc * 128 + ic) * 9 + p];
}

// ============================================================================
// Implicit-GEMM conv + bias + BN + ReLU + fused maxpool2.
// in: NHWC [nb][HW][HW][IC], wt: [9][IC][OC].
// M-tile = 48 spatial positions = (48/HW) full rows -> pool within block.
// BN=OC, BK=32. 256 threads as 16x16, micro-tile 3 x NPT.
// conv2: HW=24 IC=256 OC=128 NPT=8 -> out NHWC.
// conv3: HW=12 IC=128 OC=64  NPT=4 -> out NCHW (flatten order for fc1).
// ============================================================================
template <int HW, int IC, int OC, int NPT, bool NCHW_OUT>
__global__ __launch_bounds__(256) void k_conv(
    const float* __restrict__ in, const float* __restrict__ wt,
    const float* __restrict__ cb, const float* __restrict__ g,
    const float* __restrict__ bb, const float* __restrict__ m,
    const float* __restrict__ v, float* __restrict__ out) {
  constexpr int BM = 48, BK = 32;
  constexpr int ROWS = BM / HW;     // h-rows per tile: 2 (conv2) / 4 (conv3)
  constexpr int TILES = HW / ROWS;  // tiles per image: 12 / 3
  constexpr int APITCH = BM + 1;    // 49: breaks LDS write conflicts
  constexpr int ASZ = BK * APITCH;
  constexpr int EPITCH = OC + 1;
  constexpr int SMEM =
      (ASZ + BK * OC) > (BM * EPITCH) ? (ASZ + BK * OC) : (BM * EPITCH);
  __shared__ float smem[SMEM];
  float* As = smem;        // [BK][APITCH], k-major
  float* Bs = smem + ASZ;  // [BK][OC]
  const int b = blockIdx.x / TILES;
  const int T = blockIdx.x - b * TILES;
  const int h0 = T * ROWS;
  const int tid = threadIdx.x;
  const int ty = tid >> 4, tx = tid & 15;
  float acc[3][NPT];
#pragma unroll
  for (int i = 0; i < 3; i++)
#pragma unroll
    for (int j = 0; j < NPT; j++) acc[i][j] = 0.f;

  const float* inb = in + (size_t)b * HW * HW * IC;

  for (int p = 0; p < 9; p++) {
    const int kh = p / 3 - 1, kw = p % 3 - 1;
    for (int kc = 0; kc < IC; kc += BK) {
      // ---- A tile: 48 m-rows x 32 ic (float2 per thread-slot, zero-padded)
#pragma unroll
      for (int i = 0; i < 3; i++) {
        int s = tid + 256 * i;  // 0..767
        int ml = s >> 4, sl = s & 15;
        int h = h0 + ml / HW, wcol = ml % HW;
        int ih = h + kh, iw = wcol + kw;
        float2 val = make_float2(0.f, 0.f);
        if (ih >= 0 && ih < HW && iw >= 0 && iw < HW)
          val = *(const float2*)&inb[((ih * HW + iw) * IC) + kc + sl * 2];
        As[(sl * 2) * APITCH + ml] = val.x;
        As[(sl * 2 + 1) * APITCH + ml] = val.y;
      }
      // ---- B tile: 32 k x OC, coalesced float4
#pragma unroll
      for (int i = 0; i < BK * OC / 4 / 256; i++) {
        int s = tid + 256 * i;
        int k = s / (OC / 4), oc4 = s - k * (OC / 4);
        float4 val = *(const float4*)&wt[((p * IC + kc + k) * OC) + oc4 * 4];
        *(float4*)&Bs[k * OC + oc4 * 4] = val;
      }
      __syncthreads();
#pragma unroll 8
      for (int k = 0; k < BK; k++) {
        float a0 = As[k * APITCH + ty * 3 + 0];
        float a1 = As[k * APITCH + ty * 3 + 1];
        float a2 = As[k * APITCH + ty * 3 + 2];
        float bv[NPT];
#pragma unroll
        for (int j = 0; j < NPT; j++) bv[j] = Bs[k * OC + tx * NPT + j];
#pragma unroll
        for (int j = 0; j < NPT; j++) {
          acc[0][j] = fmaf(a0, bv[j], acc[0][j]);
          acc[1][j] = fmaf(a1, bv[j], acc[1][j]);
          acc[2][j] = fmaf(a2, bv[j], acc[2][j]);
        }
      }
      __syncthreads();
    }
  }
  // ---- epilogue: BN + ReLU into LDS tile E (aliases As/Bs, sync'd above)
  float* E = smem;  // [BM][EPITCH]
#pragma unroll
  for (int j = 0; j < NPT; j++) {
    int oc = tx * NPT + j;
    float scale = g[oc] * rsqrtf(v[oc] + EPS_BN);
    float bias = (cb[oc] - m[oc]) * scale + bb[oc];
#pragma unroll
    for (int i = 0; i < 3; i++) {
      int ml = ty * 3 + i;
      E[ml * EPITCH + oc] = fmaxf(acc[i][j] * scale + bias, 0.f);
    }
  }
  __syncthreads();
  // ---- 2x2 maxpool + store
  constexpr int OHW = HW / 2;
  constexpr int NP = (ROWS / 2) * OHW * OC;
  for (int s = tid; s < NP; s += 256) {
    int oc = s % OC;
    int ow = (s / OC) % OHW;
    int ohl = s / (OC * OHW);
    int m00 = (2 * ohl) * HW + 2 * ow;
    float x0 = E[m00 * EPITCH + oc];
    float x1 = E[(m00 + 1) * EPITCH + oc];
    float x2 = E[(m00 + HW) * EPITCH + oc];
    float x3 = E[(m00 + HW + 1) * EPITCH + oc];
    float mx = fmaxf(fmaxf(x0, x1), fmaxf(x2, x3));
    int oh = (h0 >> 1) + ohl;
    if (NCHW_OUT)
      out[(((size_t)b * OC + oc) * OHW + oh) * OHW + ow] = mx;
    else
      out[(((size_t)b * OHW + oh) * OHW + ow) * OC + oc] = mx;
  }
}

// ============================================================================
// FC chain collapse (no activations between fc1/fc2/att => pure linear):
//   W32  = att_w[64,256] @ fc2_w[256,512]
//   W_eff= W32[64,512]   @ fc1_w[512,2304]
//   b_eff= W32@fc1_b + att_w@fc2_b + att_b
//   q    = out4[512,2304] @ W_eff^T + b_eff
// ============================================================================
__global__ void k_w32(const float* __restrict__ A3, const float* __restrict__ A2,
                      float* __restrict__ W32) {
  int idx = blockIdx.x * 256 + threadIdx.x;  // 64*512
  int r = idx >> 9, c = idx & 511;
  float s = 0.f;
  for (int k = 0; k < 256; k++) s = fmaf(A3[r * 256 + k], A2[k * 512 + c], s);
  W32[idx] = s;
}
__global__ void k_weff(const float* __restrict__ W32, const float* __restrict__ A1,
                       float* __restrict__ We) {
  int idx = blockIdx.x * 256 + threadIdx.x;  // 64*2304 (2304%256==0: no straddle)
  int r = idx / 2304, c = idx - r * 2304;
  float s = 0.f;
  for (int k = 0; k < 512; k++) s = fmaf(W32[r * 512 + k], A1[k * 2304 + c], s);
  We[idx] = s;
}
__global__ void k_beff(const float* __restrict__ W32, const float* __restrict__ b1,
                       const float* __restrict__ A3, const float* __restrict__ b2,
                       const float* __restrict__ b3, float* __restrict__ be) {
  int r = threadIdx.x;  // 64 threads
  float s = b3[r];
  for (int k = 0; k < 512; k++) s = fmaf(W32[r * 512 + k], b1[k], s);
  for (int k = 0; k < 256; k++) s = fmaf(A3[r * 256 + k], b2[k], s);
  be[r] = s;
}
__global__ __launch_bounds__(256) void k_q(const float* __restrict__ X,
                                           const float* __restrict__ We,
                                           const float* __restrict__ be,
                                           float* __restrict__ q) {
  // block = 4 images x 64 outputs; X row broadcast, We rows L2-streamed
  int n = threadIdx.x & 63;
  int b = blockIdx.x * 4 + (threadIdx.x >> 6);
  const float* xr = X + (size_t)b * 2304;
  const float* wr = We + (size_t)n * 2304;
  float s = be[n];
  for (int k = 0; k < 2304; k++) s = fmaf(xr[k], wr[k], s);
  q[b * 64 + n] = s;
}

// ============================================================================
// Spatial attention + fc3. One wave per image.
// scores[hw] = sum_c out3[b,c,hw]*q[b,c]; softmax(36); g = out3 @ attn; fc3.
// out3 is NCHW [512][64][6][6].
// ============================================================================
__global__ __launch_bounds__(64) void k_attn(
    const float* __restrict__ out3, const float* __restrict__ q,
    const float* __restrict__ w3, const float* __restrict__ b3,
    float* __restrict__ out) {
  int b = blockIdx.x, t = threadIdx.x;
  __shared__ float ql[64], sc[36], gm[64];
  const float* o3 = out3 + (size_t)b * 2304;
  ql[t] = q[b * 64 + t];
  __syncthreads();
  float s = -INFINITY;
  if (t < 36) {
    float acc = 0.f;
    for (int c = 0; c < 64; c++) acc = fmaf(o3[c * 36 + t], ql[c], acc);
    s = acc;
  }
  float mx = s;
  for (int off = 32; off >= 1; off >>= 1) mx = fmaxf(mx, __shfl_xor(mx, off));
  float e = (t < 36) ? expf(s - mx) : 0.f;
  float sum = e;
  for (int off = 32; off >= 1; off >>= 1) sum += __shfl_xor(sum, off);
  if (t < 36) sc[t] = e / sum;
  __syncthreads();
  float gv = 0.f;
  for (int hw = 0; hw < 36; hw++) gv = fmaf(o3[t * 36 + hw], sc[hw], gv);
  gm[t] = gv;
  __syncthreads();
  if (t < 7) {
    float acc = b3[t];
    for (int c = 0; c < 64; c++) acc = fmaf(w3[t * 64 + c], gm[c], acc);
    out[b * 7 + t] = acc;
  }
}

// ============================================================================
extern "C" void kernel_launch(void* const* d_in, const int* in_sizes, int n_in,
                              void* d_out, int out_size, void* d_ws,
                              size_t ws_size, hipStream_t stream) {
  const float* x    = (const float*)d_in[0];
  const float* c1w  = (const float*)d_in[1];
  const float* c1b  = (const float*)d_in[2];
  const float* g1   = (const float*)d_in[3];
  const float* bb1  = (const float*)d_in[4];
  const float* m1   = (const float*)d_in[5];
  const float* v1   = (const float*)d_in[6];
  const float* c2w  = (const float*)d_in[7];
  const float* c2b  = (const float*)d_in[8];
  const float* g2   = (const float*)d_in[9];
  const float* bb2  = (const float*)d_in[10];
  const float* m2   = (const float*)d_in[11];
  const float* v2   = (const float*)d_in[12];
  const float* c3w  = (const float*)d_in[13];
  const float* c3b  = (const float*)d_in[14];
  const float* g3   = (const float*)d_in[15];
  const float* bb3  = (const float*)d_in[16];
  const float* m3   = (const float*)d_in[17];
  const float* v3   = (const float*)d_in[18];
  const float* fc1w = (const float*)d_in[19];
  const float* fc1b = (const float*)d_in[20];
  const float* fc2w = (const float*)d_in[21];
  const float* fc2b = (const float*)d_in[22];
  const float* attw = (const float*)d_in[23];
  const float* attb = (const float*)d_in[24];
  const float* fc3w = (const float*)d_in[25];
  const float* fc3b = (const float*)d_in[26];

  // ---- adaptive batch chunking: pick largest CH whose footprint fits ws_size
  // per-chunk floats: out1 CH*147456 (NHWC fp32) + out2 CH*18432
  // persistent floats: out3 1179648 + w2t 294912 + w3t 73728 + W32 32768
  //                  + We 147456 + be 64 + q 32768  (+ slack)
  const size_t PERSIST = 1179648 + 294912 + 73728 + 32768 + 147456 + 64 + 32768;
  int CH = 512;
  while (CH > 8 &&
         ((size_t)CH * (147456 + 18432) + PERSIST + 1024) * 4 > ws_size)
    CH >>= 1;
  const int NCHK = 512 / CH;

  float* ws = (float*)d_ws;
  size_t o = 0;
  float* out1 = ws + o; o += (size_t)CH * 147456;  // NHWC [CH,24,24,256]
  float* out2 = ws + o; o += (size_t)CH * 18432;   // NHWC [CH,12,12,128]
  float* out3 = ws + o; o += 1179648;              // NCHW [512,64,6,6]
  float* w2t  = ws + o; o += 294912;
  float* w3t  = ws + o; o += 73728;
  float* W32  = ws + o; o += 32768;
  float* We   = ws + o; o += 147456;
  float* be   = ws + o; o += 64;
  float* q    = ws + o; o += 32768;

  // weight prep + FC collapse (independent of conv pipeline)
  k_tw2<<<1152, 256, 0, stream>>>(c2w, w2t);
  k_tw3<<<288, 256, 0, stream>>>(c3w, w3t);
  k_w32<<<128, 256, 0, stream>>>(attw, fc2w, W32);
  k_weff<<<576, 256, 0, stream>>>(W32, fc1w, We);
  k_beff<<<1, 64, 0, stream>>>(W32, fc1b, attw, fc2b, attb, be);

  // conv pipeline, chunked over batch; out1/out2 buffers reused per chunk
  for (int c = 0; c < NCHK; c++) {
    const float* xc = x + (size_t)c * CH * 2304;
    float* o3c = out3 + (size_t)c * CH * 2304;
    k_conv1<<<CH, 256, 0, stream>>>(xc, c1w, c1b, g1, bb1, m1, v1, out1);
    k_conv<24, 256, 128, 8, false>
        <<<CH * 12, 256, 0, stream>>>(out1, w2t, c2b, g2, bb2, m2, v2, out2);
    k_conv<12, 128, 64, 4, true>
        <<<CH * 3, 256, 0, stream>>>(out2, w3t, c3b, g3, bb3, m3, v3, o3c);
  }

  // attention tail on full batch
  k_q<<<128, 256, 0, stream>>>(out3, We, be, q);
  k_attn<<<512, 64, 0, stream>>>(out3, q, fc3w, fc3b, (float*)d_out);
}

// Round 3
// 997.661 us; speedup vs baseline: 3.1265x; 3.1265x over previous
//
#include <hip/hip_runtime.h>
#include <hip/hip_bf16.h>
#include <math.h>

#define EPS_BN 1e-5f

typedef __bf16 bf16x8 __attribute__((ext_vector_type(8)));
typedef float f32x4 __attribute__((ext_vector_type(4)));

// ============================================================================
// conv1 + bias + BN + ReLU + maxpool2: x[CH,1,48,48] fp32 ->
// out1p PADDED bf16 NHWC [CH][26][26][256] with zero halo (for conv2 MFMA A).
// One block per image; thread = output channel.
// ============================================================================
__global__ __launch_bounds__(256) void k_conv1(
    const float* __restrict__ x, const float* __restrict__ w,
    const float* __restrict__ cb, const float* __restrict__ g,
    const float* __restrict__ bb, const float* __restrict__ m,
    const float* __restrict__ v, __hip_bfloat16* __restrict__ out1p) {
  __shared__ float xp[50 * 50];
  const int b = blockIdx.x;
  const int t = threadIdx.x;
  __hip_bfloat16* ob = out1p + (size_t)b * (26 * 26 * 256);
  const __hip_bfloat16 z = __float2bfloat16(0.f);
  // halo zero: rows 0 & 25 (26*256 each), cols 0 & 25 for rows 1..24
  for (int i = t; i < 26 * 256; i += 256) {
    ob[i] = z;
    ob[25 * 26 * 256 + i] = z;
  }
  for (int i = t; i < 24 * 2 * 256; i += 256) {
    int r = 1 + (i >> 9), side = (i >> 8) & 1, c = i & 255;
    ob[(r * 26 + side * 25) * 256 + c] = z;
  }
  for (int i = t; i < 2500; i += 256) xp[i] = 0.f;
  __syncthreads();
  const float* xb = x + (size_t)b * 2304;
  for (int i = t; i < 2304; i += 256) {
    int r = i / 48, c = i - r * 48;
    xp[(r + 1) * 50 + (c + 1)] = xb[i];
  }
  __syncthreads();
  float wr[9];
#pragma unroll
  for (int i = 0; i < 9; i++) wr[i] = w[t * 9 + i];
  const float scale = g[t] * rsqrtf(v[t] + EPS_BN);
  const float bias = (cb[t] - m[t]) * scale + bb[t];
  for (int oh = 0; oh < 24; oh++) {
    for (int ow = 0; ow < 24; ow++) {
      float p[4][4];
#pragma unroll
      for (int r = 0; r < 4; r++)
#pragma unroll
        for (int c = 0; c < 4; c++)
          p[r][c] = xp[(2 * oh + r) * 50 + (2 * ow + c)];
      float s4[4];
      int ii = 0;
#pragma unroll
      for (int dh = 0; dh < 2; dh++)
#pragma unroll
        for (int dw = 0; dw < 2; dw++, ii++) {
          float s = 0.f;
#pragma unroll
          for (int kh = 0; kh < 3; kh++)
#pragma unroll
            for (int kw = 0; kw < 3; kw++)
              s = fmaf(p[dh + kh][dw + kw], wr[kh * 3 + kw], s);
          s4[ii] = s * scale + bias;  // BN before pool (scale may be negative)
        }
      float mx = fmaxf(fmaxf(s4[0], s4[1]), fmaxf(s4[2], s4[3]));
      ob[((oh + 1) * 26 + (ow + 1)) * 256 + t] =
          __float2bfloat16(fmaxf(mx, 0.f));
    }
  }
}

// ============================================================================
// Weight prep: w [OC][IC][3][3] fp32 -> bf16 interleaved [9][IC/8][OC][8]
// (so a B-fragment = 16 contiguous bytes per lane: 8 ic for one oc).
// ============================================================================
template <int IC, int OC>
__global__ void k_twi(const float* __restrict__ w,
                      __hip_bfloat16* __restrict__ wt) {
  int idx = blockIdx.x * 256 + threadIdx.x;
  if (idx >= 9 * IC * OC) return;
  int icr = idx & 7;
  int oc = (idx >> 3) % OC;
  int rest = (idx >> 3) / OC;
  int icg = rest % (IC / 8);
  int p = rest / (IC / 8);
  int ic = icg * 8 + icr;
  wt[idx] = __float2bfloat16(w[(oc * IC + ic) * 9 + p]);
}

// zero the halo of padded out2p [CH][14][14][128] bf16 (conv2 writes interior)
__global__ void k_halo2(__hip_bfloat16* __restrict__ out2p) {
  int b = blockIdx.x, t = threadIdx.x;
  __hip_bfloat16* ob = out2p + (size_t)b * (14 * 14 * 128);
  const __hip_bfloat16 z = __float2bfloat16(0.f);
  for (int i = t; i < 14 * 128; i += 256) {
    ob[i] = z;
    ob[13 * 14 * 128 + i] = z;
  }
  for (int i = t; i < 12 * 2 * 128; i += 256) {
    int r = 1 + (i >> 8), side = (i >> 7) & 1, c = i & 127;
    ob[(r * 14 + side * 13) * 128 + c] = z;
  }
}

// ============================================================================
// MFMA implicit-GEMM conv + bias + BN + ReLU + fused maxpool2 (bf16 in, fp32 acc)
// in:  padded bf16 NHWC [nb][HP][HP][IC]  (HP = HW+2, zero halo)
// wt:  bf16 [9][IC/8][OC][8]
// Block tile: M = NW_M*48 spatial positions x N = OC. 4 waves as NW_M x NW_N.
// Wave tile: 48 x (OC/NW_N) using 16x16x32 MFMA (3 m-frags x NF n-frags).
// A staged in LDS as [kg(8)][MT][8] bf16 per BK=64 stage (conflict-free b128);
// B fragments loaded per-lane direct from global (L2-resident, disjoint n).
// Epilogue: BN+ReLU -> LDS E [48][OC+1] per m-half, 2x2 maxpool, store.
// conv2: HW=24 IC=256 OC=128 2x2 -> padded bf16 NHWC [14][14][128]
// conv3: HW=12 IC=128 OC=64  1x4 -> fp32 NCHW [64][6][6] (flatten order for q)
// ============================================================================
template <int HW, int IC, int OC, int NW_M, int NW_N, bool NCHW_OUT>
__global__ __launch_bounds__(256, 4) void k_mconv(
    const __hip_bfloat16* __restrict__ in, const __hip_bfloat16* __restrict__ wt,
    const float* __restrict__ cb, const float* __restrict__ gg,
    const float* __restrict__ bbv, const float* __restrict__ bm,
    const float* __restrict__ bv, void* __restrict__ outp) {
  constexpr int HP = HW + 2;
  constexpr int MT = NW_M * 48;           // block M rows
  constexpr int ROWS = MT / HW;           // h-rows per block (4)
  constexpr int TILES = HW / ROWS;        // blocks per image
  constexpr int WN = OC / NW_N;           // wave N width
  constexpr int NF = WN / 16;             // n-frags per wave
  constexpr int NCH = MT * 8;             // A 16B-chunks per BK=64 stage
  constexpr int NCHP = (NCH + 255) & ~255;
  constexpr int NLD = NCHP / 256;         // staging chunks per thread
  constexpr int EPITCH = OC + 1;

  __shared__ __align__(16) union {
    unsigned short a[NCHP * 8];           // [kg 0..7][MT][8] bf16 (+pad)
    float e[48 * EPITCH];
  } sm;

  const int tid = threadIdx.x;
  const int wv = tid >> 6, ln = tid & 63;
  const int wm = (NW_M == 2) ? (wv >> 1) : 0;
  const int wn = (NW_M == 2) ? (wv & 1) : wv;
  const int lhi = ln >> 4, llo = ln & 15;

  const int b = blockIdx.x / TILES;
  const int T = blockIdx.x - b * TILES;
  const int h0 = T * ROWS;

  const __hip_bfloat16* inb = in + (size_t)b * HP * HP * IC;

  // staging precompute: chunk c = tid + i*256 -> (kg, m) -> source row base
  int rowbase[NLD], ldsoff[NLD];
#pragma unroll
  for (int i = 0; i < NLD; i++) {
    int c = tid + i * 256;
    ldsoff[i] = c * 8;                    // dest (ushort units), pad chunks ok
    if (c >= NCH) c = NCH - 1;            // clamp source (dup read, dest=pad)
    int kg = c / MT, mm = c % MT;
    int hl = mm / HW, wl = mm % HW;
    rowbase[i] = ((h0 + hl) * HP + wl) * IC + kg * 8;
  }
  // A-frag LDS read base: (kg*MT + m)*8 ushorts, kg = lhi (+4 per ks)
  const int aread0 = (lhi * MT + wm * 48 + llo) * 8;
  // B lane-part offsets (elements)
  int boff[NF];
#pragma unroll
  for (int j = 0; j < NF; j++)
    boff[j] = (lhi * OC + wn * WN + j * 16 + llo) * 8;

  f32x4 acc[3][NF];
  const f32x4 fz = {0.f, 0.f, 0.f, 0.f};
#pragma unroll
  for (int i = 0; i < 3; i++)
#pragma unroll
    for (int j = 0; j < NF; j++) acc[i][j] = fz;

  for (int p = 0; p < 9; p++) {
    const int ph = p / 3, pw = p % 3;
    const int pbase = (ph * HP + pw) * IC;
    for (int kc = 0; kc < IC; kc += 64) {
      uint4 sv[NLD];
#pragma unroll
      for (int i = 0; i < NLD; i++)
        sv[i] = *(const uint4*)(inb + rowbase[i] + pbase + kc);
      __syncthreads();  // prior stage's LDS reads done
#pragma unroll
      for (int i = 0; i < NLD; i++) *(uint4*)&sm.a[ldsoff[i]] = sv[i];
      __syncthreads();
#pragma unroll
      for (int ks = 0; ks < 2; ks++) {
        const int kb = (p * (IC / 8) + (kc >> 3) + ks * 4) * OC * 8;
        bf16x8 bf[NF];
#pragma unroll
        for (int j = 0; j < NF; j++)
          bf[j] = *(const bf16x8*)(wt + kb + boff[j]);
        bf16x8 af[3];
#pragma unroll
        for (int mt = 0; mt < 3; mt++)
          af[mt] = *(const bf16x8*)&sm.a[aread0 + (ks * 4 * MT + mt * 16) * 8];
#pragma unroll
        for (int mt = 0; mt < 3; mt++)
#pragma unroll
          for (int j = 0; j < NF; j++)
            acc[mt][j] = __builtin_amdgcn_mfma_f32_16x16x32_bf16(
                af[mt], bf[j], acc[mt][j], 0, 0, 0);
      }
    }
  }

  // ---- epilogue: per m-half pass: BN+ReLU -> E, 2x2 pool, store
  constexpr int PR = 48 / HW;             // h-rows per pass
  constexpr int POH = PR / 2;
  constexpr int OHW = HW / 2;
  constexpr int NP = POH * OHW * OC;
#pragma unroll
  for (int a = 0; a < NW_M; a++) {
    __syncthreads();                      // protect sm vs prior reads
    if (wm == a) {
#pragma unroll
      for (int j = 0; j < NF; j++) {
        int n = wn * WN + j * 16 + llo;
        float scale = gg[n] * rsqrtf(bv[n] + EPS_BN);
        float bias = (cb[n] - bm[n]) * scale + bbv[n];
#pragma unroll
        for (int mt = 0; mt < 3; mt++)
#pragma unroll
          for (int r = 0; r < 4; r++) {
            int mrow = mt * 16 + lhi * 4 + r;  // within pass's 48
            sm.e[mrow * EPITCH + n] =
                fmaxf(acc[mt][j][r] * scale + bias, 0.f);
          }
      }
    }
    __syncthreads();
    for (int s = tid; s < NP; s += 256) {
      int n = s % OC;
      int ow = (s / OC) % OHW;
      int ohl = s / (OC * OHW);
      int mloc = (2 * ohl) * HW + 2 * ow;
      float x0 = sm.e[mloc * EPITCH + n];
      float x1 = sm.e[(mloc + 1) * EPITCH + n];
      float x2 = sm.e[(mloc + HW) * EPITCH + n];
      float x3 = sm.e[(mloc + HW + 1) * EPITCH + n];
      float mx = fmaxf(fmaxf(x0, x1), fmaxf(x2, x3));
      int oh = (h0 >> 1) + a * POH + ohl;
      if (NCHW_OUT) {
        ((float*)outp)[(((size_t)b * OC + n) * OHW + oh) * OHW + ow] = mx;
      } else {  // padded bf16 NHWC [OHW+2][OHW+2][OC], interior at +1
        ((__hip_bfloat16*)
             outp)[(((size_t)b * (OHW + 2) + oh + 1) * (OHW + 2) + ow + 1) *
                       OC +
                   n] = __float2bfloat16(mx);
      }
    }
  }
}

// ============================================================================
// FC chain collapse (pure linear): W32 = att_w@fc2_w; W_eff = W32@fc1_w;
// b_eff = W32@fc1_b + att_w@fc2_b + att_b; q = out4 @ W_eff^T + b_eff
// ============================================================================
__global__ void k_w32(const float* __restrict__ A3, const float* __restrict__ A2,
                      float* __restrict__ W32) {
  int idx = blockIdx.x * 256 + threadIdx.x;  // 64*512
  int r = idx >> 9, c = idx & 511;
  float s = 0.f;
  for (int k = 0; k < 256; k++) s = fmaf(A3[r * 256 + k], A2[k * 512 + c], s);
  W32[idx] = s;
}
__global__ void k_weff(const float* __restrict__ W32, const float* __restrict__ A1,
                       float* __restrict__ We) {
  int idx = blockIdx.x * 256 + threadIdx.x;  // 64*2304
  int r = idx / 2304, c = idx - r * 2304;
  float s = 0.f;
  for (int k = 0; k < 512; k++) s = fmaf(W32[r * 512 + k], A1[k * 2304 + c], s);
  We[idx] = s;
}
__global__ void k_beff(const float* __restrict__ W32, const float* __restrict__ b1,
                       const float* __restrict__ A3, const float* __restrict__ b2,
                       const float* __restrict__ b3, float* __restrict__ be) {
  int r = threadIdx.x;  // 64
  float s = b3[r];
  for (int k = 0; k < 512; k++) s = fmaf(W32[r * 512 + k], b1[k], s);
  for (int k = 0; k < 256; k++) s = fmaf(A3[r * 256 + k], b2[k], s);
  be[r] = s;
}
__global__ __launch_bounds__(256) void k_q(const float* __restrict__ X,
                                           const float* __restrict__ We,
                                           const float* __restrict__ be,
                                           float* __restrict__ q) {
  int n = threadIdx.x & 63;
  int b = blockIdx.x * 4 + (threadIdx.x >> 6);
  const float* xr = X + (size_t)b * 2304;
  const float* wr = We + (size_t)n * 2304;
  float s = be[n];
  for (int k = 0; k < 2304; k++) s = fmaf(xr[k], wr[k], s);
  q[b * 64 + n] = s;
}

// ============================================================================
// Spatial attention + fc3. One wave per image. out3 NCHW fp32 [512][64][6][6].
// ============================================================================
__global__ __launch_bounds__(64) void k_attn(
    const float* __restrict__ out3, const float* __restrict__ q,
    const float* __restrict__ w3, const float* __restrict__ b3,
    float* __restrict__ out) {
  int b = blockIdx.x, t = threadIdx.x;
  __shared__ float ql[64], sc[36], gm[64];
  const float* o3 = out3 + (size_t)b * 2304;
  ql[t] = q[b * 64 + t];
  __syncthreads();
  float s = -INFINITY;
  if (t < 36) {
    float acc = 0.f;
    for (int c = 0; c < 64; c++) acc = fmaf(o3[c * 36 + t], ql[c], acc);
    s = acc;
  }
  float mx = s;
  for (int off = 32; off >= 1; off >>= 1) mx = fmaxf(mx, __shfl_xor(mx, off));
  float e = (t < 36) ? expf(s - mx) : 0.f;
  float sum = e;
  for (int off = 32; off >= 1; off >>= 1) sum += __shfl_xor(sum, off);
  if (t < 36) sc[t] = e / sum;
  __syncthreads();
  float gv = 0.f;
  for (int hw = 0; hw < 36; hw++) gv = fmaf(o3[t * 36 + hw], sc[hw], gv);
  gm[t] = gv;
  __syncthreads();
  if (t < 7) {
    float acc = b3[t];
    for (int c = 0; c < 64; c++) acc = fmaf(w3[t * 64 + c], gm[c], acc);
    out[b * 7 + t] = acc;
  }
}

// ============================================================================
extern "C" void kernel_launch(void* const* d_in, const int* in_sizes, int n_in,
                              void* d_out, int out_size, void* d_ws,
                              size_t ws_size, hipStream_t stream) {
  const float* x    = (const float*)d_in[0];
  const float* c1w  = (const float*)d_in[1];
  const float* c1b  = (const float*)d_in[2];
  const float* g1   = (const float*)d_in[3];
  const float* bb1  = (const float*)d_in[4];
  const float* m1   = (const float*)d_in[5];
  const float* v1   = (const float*)d_in[6];
  const float* c2w  = (const float*)d_in[7];
  const float* c2b  = (const float*)d_in[8];
  const float* g2   = (const float*)d_in[9];
  const float* bb2  = (const float*)d_in[10];
  const float* m2   = (const float*)d_in[11];
  const float* v2   = (const float*)d_in[12];
  const float* c3w  = (const float*)d_in[13];
  const float* c3b  = (const float*)d_in[14];
  const float* g3   = (const float*)d_in[15];
  const float* bb3  = (const float*)d_in[16];
  const float* m3   = (const float*)d_in[17];
  const float* v3   = (const float*)d_in[18];
  const float* fc1w = (const float*)d_in[19];
  const float* fc1b = (const float*)d_in[20];
  const float* fc2w = (const float*)d_in[21];
  const float* fc2b = (const float*)d_in[22];
  const float* attw = (const float*)d_in[23];
  const float* attb = (const float*)d_in[24];
  const float* fc3w = (const float*)d_in[25];
  const float* fc3b = (const float*)d_in[26];

  // chunking: per-chunk bf16 bufs out1p CH*173056 + out2p CH*25088 elems
  const size_t PER_CHUNK = (173056ULL + 25088ULL) * 2;  // bytes per image
  const size_t PERSIST = 4718592 + 589824 + 147456 + 131072 + 589824 + 256 +
                         131072 + 8192;  // out3+wt2+wt3+W32+We+be+q+align
  int CH = 512;
  while (CH > 8 && (size_t)CH * PER_CHUNK + PERSIST > ws_size) CH >>= 1;
  const int NCHK = 512 / CH;

  char* base = (char*)d_ws;
  size_t off = 0;
  auto alloc = [&](size_t nbytes) -> void* {
    void* p = base + off;
    off = (off + nbytes + 255) & ~(size_t)255;
    return p;
  };
  __hip_bfloat16* out1p = (__hip_bfloat16*)alloc((size_t)CH * 173056 * 2);
  __hip_bfloat16* out2p = (__hip_bfloat16*)alloc((size_t)CH * 25088 * 2);
  float* out3          = (float*)alloc(4718592);
  __hip_bfloat16* wt2  = (__hip_bfloat16*)alloc(589824);
  __hip_bfloat16* wt3  = (__hip_bfloat16*)alloc(147456);
  float* W32           = (float*)alloc(131072);
  float* We            = (float*)alloc(589824);
  float* be            = (float*)alloc(256);
  float* q             = (float*)alloc(131072);

  // weight prep + FC collapse
  k_twi<256, 128><<<1152, 256, 0, stream>>>(c2w, wt2);
  k_twi<128, 64><<<288, 256, 0, stream>>>(c3w, wt3);
  k_w32<<<128, 256, 0, stream>>>(attw, fc2w, W32);
  k_weff<<<576, 256, 0, stream>>>(W32, fc1w, We);
  k_beff<<<1, 64, 0, stream>>>(W32, fc1b, attw, fc2b, attb, be);

  for (int c = 0; c < NCHK; c++) {
    const float* xc = x + (size_t)c * CH * 2304;
    float* o3c = out3 + (size_t)c * CH * 2304;
    k_conv1<<<CH, 256, 0, stream>>>(xc, c1w, c1b, g1, bb1, m1, v1, out1p);
    k_halo2<<<CH, 256, 0, stream>>>(out2p);
    k_mconv<24, 256, 128, 2, 2, false>
        <<<CH * 6, 256, 0, stream>>>(out1p, wt2, c2b, g2, bb2, m2, v2, out2p);
    k_mconv<12, 128, 64, 1, 4, true>
        <<<CH * 3, 256, 0, stream>>>(out2p, wt3, c3b, g3, bb3, m3, v3, o3c);
  }

  k_q<<<128, 256, 0, stream>>>(out3, We, be, q);
  k_attn<<<512, 64, 0, stream>>>(out3, q, fc3w, fc3b, (float*)d_out);
}

// Round 4
// 663.791 us; speedup vs baseline: 4.6990x; 1.5030x over previous
//
#include <hip/hip_runtime.h>
#include <hip/hip_bf16.h>
#include <math.h>

#define EPS_BN 1e-5f

typedef __bf16 bf16x8 __attribute__((ext_vector_type(8)));
typedef float f32x4 __attribute__((ext_vector_type(4)));

// ============================================================================
// conv1 + bias + BN + ReLU + maxpool2: x[CH,1,48,48] fp32 ->
// out1p PADDED bf16 NHWC [CH][26][26][256] with zero halo (for conv2 MFMA A).
// One block per image; thread = output channel.
// ============================================================================
__global__ __launch_bounds__(256) void k_conv1(
    const float* __restrict__ x, const float* __restrict__ w,
    const float* __restrict__ cb, const float* __restrict__ g,
    const float* __restrict__ bb, const float* __restrict__ m,
    const float* __restrict__ v, __hip_bfloat16* __restrict__ out1p) {
  __shared__ float xp[50 * 50];
  const int b = blockIdx.x;
  const int t = threadIdx.x;
  __hip_bfloat16* ob = out1p + (size_t)b * (26 * 26 * 256);
  const __hip_bfloat16 z = __float2bfloat16(0.f);
  for (int i = t; i < 26 * 256; i += 256) {
    ob[i] = z;
    ob[25 * 26 * 256 + i] = z;
  }
  for (int i = t; i < 24 * 2 * 256; i += 256) {
    int r = 1 + (i >> 9), side = (i >> 8) & 1, c = i & 255;
    ob[(r * 26 + side * 25) * 256 + c] = z;
  }
  for (int i = t; i < 2500; i += 256) xp[i] = 0.f;
  __syncthreads();
  const float* xb = x + (size_t)b * 2304;
  for (int i = t; i < 2304; i += 256) {
    int r = i / 48, c = i - r * 48;
    xp[(r + 1) * 50 + (c + 1)] = xb[i];
  }
  __syncthreads();
  float wr[9];
#pragma unroll
  for (int i = 0; i < 9; i++) wr[i] = w[t * 9 + i];
  const float scale = g[t] * rsqrtf(v[t] + EPS_BN);
  const float bias = (cb[t] - m[t]) * scale + bb[t];
  for (int oh = 0; oh < 24; oh++) {
    for (int ow = 0; ow < 24; ow++) {
      float p[4][4];
#pragma unroll
      for (int r = 0; r < 4; r++)
#pragma unroll
        for (int c = 0; c < 4; c++)
          p[r][c] = xp[(2 * oh + r) * 50 + (2 * ow + c)];
      float s4[4];
      int ii = 0;
#pragma unroll
      for (int dh = 0; dh < 2; dh++)
#pragma unroll
        for (int dw = 0; dw < 2; dw++, ii++) {
          float s = 0.f;
#pragma unroll
          for (int kh = 0; kh < 3; kh++)
#pragma unroll
            for (int kw = 0; kw < 3; kw++)
              s = fmaf(p[dh + kh][dw + kw], wr[kh * 3 + kw], s);
          s4[ii] = s * scale + bias;  // BN before pool (scale may be negative)
        }
      float mx = fmaxf(fmaxf(s4[0], s4[1]), fmaxf(s4[2], s4[3]));
      ob[((oh + 1) * 26 + (ow + 1)) * 256 + t] =
          __float2bfloat16(fmaxf(mx, 0.f));
    }
  }
}

// ============================================================================
// Weight prep: w [OC][IC][3][3] fp32 -> bf16 interleaved [9][IC/8][OC][8]
// ============================================================================
template <int IC, int OC>
__global__ void k_twi(const float* __restrict__ w,
                      __hip_bfloat16* __restrict__ wt) {
  int idx = blockIdx.x * 256 + threadIdx.x;
  if (idx >= 9 * IC * OC) return;
  int icr = idx & 7;
  int oc = (idx >> 3) % OC;
  int rest = (idx >> 3) / OC;
  int icg = rest % (IC / 8);
  int p = rest / (IC / 8);
  int ic = icg * 8 + icr;
  wt[idx] = __float2bfloat16(w[(oc * IC + ic) * 9 + p]);
}

// zero the halo of padded out2p [CH][14][14][128] bf16 (conv2 writes interior)
__global__ void k_halo2(__hip_bfloat16* __restrict__ out2p) {
  int b = blockIdx.x, t = threadIdx.x;
  __hip_bfloat16* ob = out2p + (size_t)b * (14 * 14 * 128);
  const __hip_bfloat16 z = __float2bfloat16(0.f);
  for (int i = t; i < 14 * 128; i += 256) {
    ob[i] = z;
    ob[13 * 14 * 128 + i] = z;
  }
  for (int i = t; i < 12 * 2 * 128; i += 256) {
    int r = 1 + (i >> 8), side = (i >> 7) & 1, c = i & 127;
    ob[(r * 14 + side * 13) * 128 + c] = z;
  }
}

// ============================================================================
// MFMA implicit-GEMM conv + bias + BN + ReLU + fused maxpool2 (bf16, fp32 acc)
// in:  padded bf16 NHWC [nb][HP][HP][IC]  (HP = HW+2, zero halo)
// wt:  bf16 [9][IC/8][OC][8]
//
// A-window scheme: per kc-64 stage, stage the block's FULL padded input window
// (6 rows x CP cols x 64 ic) into LDS ONCE; all 9 filter taps read shifted
// fragments from it (compile-time offsets after full p-unroll). 5.5x less
// global A traffic and 9x fewer barriers than per-tap staging.
// LDS layout: 16B chunk (kg,r,c) at unit kg*(6*CP+1) + r*CP + c  (pad per kg
// plane => staging writes and frag reads are <=2-way bank aliased: free).
// B fragments per-lane direct from global (L2-resident weights).
// conv2: HW=24 IC=256 OC=128 waves 2x2 -> padded bf16 NHWC [14][14][128]
// conv3: HW=12 IC=128 OC=64  waves 1x4 -> fp32 NCHW [64][6][6]
// ============================================================================
template <int HW, int IC, int OC, int NW_M, int NW_N, bool NCHW_OUT>
__global__ __launch_bounds__(256) void k_mconv(
    const __hip_bfloat16* __restrict__ in, const __hip_bfloat16* __restrict__ wt,
    const float* __restrict__ cb, const float* __restrict__ gg,
    const float* __restrict__ bbv, const float* __restrict__ bm,
    const float* __restrict__ bv, void* __restrict__ outp) {
  constexpr int HP = HW + 2;
  constexpr int MT = NW_M * 48;        // block M rows
  constexpr int ROWS = MT / HW;        // output h-rows per block (4)
  constexpr int TILES = HW / ROWS;     // blocks per image
  constexpr int WN = OC / NW_N;        // wave N width
  constexpr int NF = WN / 16;          // n-frags per wave
  constexpr int CP = (HP + 15) & ~15;  // padded col count (32 / 16)
  constexpr int KGP = 6 * CP + 1;      // kg-plane pitch in 16B units (+1 pad)
  constexpr int NCH = 8 * 6 * CP;      // staged 16B chunks per kc stage
  constexpr int NLD = NCH / 256;       // chunks per thread (6 / 3)
  constexpr int EPITCH = OC + 1;
  constexpr int ABYTES = 8 * KGP * 16;
  constexpr int EBYTES = 48 * EPITCH * 4;
  constexpr int SMB = ABYTES > EBYTES ? ABYTES : EBYTES;

  __shared__ __align__(16) char smraw[SMB];
  unsigned short* sa = (unsigned short*)smraw;  // A window
  float* se = (float*)smraw;                    // epilogue tile

  const int tid = threadIdx.x;
  const int wv = tid >> 6, ln = tid & 63;
  const int wm = (NW_M == 2) ? (wv >> 1) : 0;
  const int wn = (NW_M == 2) ? (wv & 1) : wv;
  const int lhi = ln >> 4, llo = ln & 15;

  const int b = blockIdx.x / TILES;
  const int T = blockIdx.x - b * TILES;
  const int h0 = T * ROWS;  // first padded input row == first output row

  const __hip_bfloat16* inb = in + (size_t)b * HP * HP * IC;

  // staging map: chunk ci = tid + i*256, kg fastest (8 lanes -> 128B contig)
  int srcoff[NLD], dstoff[NLD];
#pragma unroll
  for (int i = 0; i < NLD; i++) {
    int ci = tid + i * 256;
    int kg = ci & 7;
    int rest = ci >> 3;
    int col = rest % CP;
    int r = rest / CP;
    int sc = col < HP ? col : HP - 1;               // clamp pad cols (unread)
    srcoff[i] = ((h0 + r) * HP + sc) * IC + kg * 8;  // elements
    dstoff[i] = (kg * KGP + r * CP + col) * 8;       // ushort units
  }
  // A-frag per-lane spatial offset (window coords) for each m-frag
  int aoff[3];
#pragma unroll
  for (int mt = 0; mt < 3; mt++) {
    int m = wm * 48 + mt * 16 + llo;
    int hl = m / HW, wl = m % HW;
    aoff[mt] = (hl * CP + wl) * 8;
  }
  const int bl0 = (wn * WN + llo) * 8;  // B lane base (elements)

  f32x4 acc[3][NF];
  const f32x4 fz = {0.f, 0.f, 0.f, 0.f};
#pragma unroll
  for (int i = 0; i < 3; i++)
#pragma unroll
    for (int j = 0; j < NF; j++) acc[i][j] = fz;

  for (int kc = 0; kc < IC; kc += 64) {
    uint4 sv[NLD];
#pragma unroll
    for (int i = 0; i < NLD; i++)
      sv[i] = *(const uint4*)(inb + srcoff[i] + kc);
    __syncthreads();  // prior stage's LDS reads done
#pragma unroll
    for (int i = 0; i < NLD; i++) *(uint4*)&sa[dstoff[i]] = sv[i];
    __syncthreads();
#pragma unroll
    for (int p = 0; p < 9; p++) {
      constexpr int ICG = IC / 8;
      const int ph = p / 3, pw = p % 3;
#pragma unroll
      for (int ks = 0; ks < 2; ks++) {
        bf16x8 bf[NF];
#pragma unroll
        for (int j = 0; j < NF; j++)
          bf[j] = *(const bf16x8*)(wt +
                                   ((p * ICG + (kc >> 3) + ks * 4 + lhi) * OC) *
                                       8 +
                                   bl0 + j * 128);
        bf16x8 af[3];
#pragma unroll
        for (int mt = 0; mt < 3; mt++)
          af[mt] = *(const bf16x8*)&sa[((ks * 4 + lhi) * KGP + ph * CP + pw) *
                                           8 +
                                       aoff[mt]];
#pragma unroll
        for (int mt = 0; mt < 3; mt++)
#pragma unroll
          for (int j = 0; j < NF; j++)
            acc[mt][j] = __builtin_amdgcn_mfma_f32_16x16x32_bf16(
                af[mt], bf[j], acc[mt][j], 0, 0, 0);
      }
    }
  }

  // ---- epilogue: per wm-pass: BN+ReLU -> E [48][EPITCH], 2x2 pool, store
  constexpr int PR = 48 / HW;  // h-rows per pass
  constexpr int POH = PR / 2;
  constexpr int OHW = HW / 2;
  constexpr int NP = POH * OHW * OC;
#pragma unroll
  for (int a = 0; a < NW_M; a++) {
    __syncthreads();  // protect smraw vs prior reads
    if (wm == a) {
#pragma unroll
      for (int j = 0; j < NF; j++) {
        int n = wn * WN + j * 16 + llo;
        float scale = gg[n] * rsqrtf(bv[n] + EPS_BN);
        float bias = (cb[n] - bm[n]) * scale + bbv[n];
#pragma unroll
        for (int mt = 0; mt < 3; mt++)
#pragma unroll
          for (int r = 0; r < 4; r++) {
            int mrow = mt * 16 + lhi * 4 + r;
            se[mrow * EPITCH + n] = fmaxf(acc[mt][j][r] * scale + bias, 0.f);
          }
      }
    }
    __syncthreads();
    for (int s = tid; s < NP; s += 256) {
      int n = s % OC;
      int ow = (s / OC) % OHW;
      int ohl = s / (OC * OHW);
      int mloc = (2 * ohl) * HW + 2 * ow;
      float x0 = se[mloc * EPITCH + n];
      float x1 = se[(mloc + 1) * EPITCH + n];
      float x2 = se[(mloc + HW) * EPITCH + n];
      float x3 = se[(mloc + HW + 1) * EPITCH + n];
      float mx = fmaxf(fmaxf(x0, x1), fmaxf(x2, x3));
      int oh = (h0 >> 1) + a * POH + ohl;
      if (NCHW_OUT) {
        ((float*)outp)[(((size_t)b * OC + n) * OHW + oh) * OHW + ow] = mx;
      } else {  // padded bf16 NHWC [OHW+2][OHW+2][OC], interior at +1
        ((__hip_bfloat16*)
             outp)[(((size_t)b * (OHW + 2) + oh + 1) * (OHW + 2) + ow + 1) *
                       OC +
                   n] = __float2bfloat16(mx);
      }
    }
  }
}

// ============================================================================
// FC chain collapse (pure linear): W32 = att_w@fc2_w; W_eff = W32@fc1_w;
// b_eff = W32@fc1_b + att_w@fc2_b + att_b; q = out4 @ W_eff^T + b_eff
// ============================================================================
__global__ void k_w32(const float* __restrict__ A3, const float* __restrict__ A2,
                      float* __restrict__ W32) {
  int idx = blockIdx.x * 256 + threadIdx.x;  // 64*512
  int r = idx >> 9, c = idx & 511;
  float s = 0.f;
  for (int k = 0; k < 256; k++) s = fmaf(A3[r * 256 + k], A2[k * 512 + c], s);
  W32[idx] = s;
}
__global__ void k_weff(const float* __restrict__ W32, const float* __restrict__ A1,
                       float* __restrict__ We) {
  int idx = blockIdx.x * 256 + threadIdx.x;  // 64*2304
  int r = idx / 2304, c = idx - r * 2304;
  float s = 0.f;
  for (int k = 0; k < 512; k++) s = fmaf(W32[r * 512 + k], A1[k * 2304 + c], s);
  We[idx] = s;
}
__global__ void k_beff(const float* __restrict__ W32, const float* __restrict__ b1,
                       const float* __restrict__ A3, const float* __restrict__ b2,
                       const float* __restrict__ b3, float* __restrict__ be) {
  int r = threadIdx.x;  // 64
  float s = b3[r];
  for (int k = 0; k < 512; k++) s = fmaf(W32[r * 512 + k], b1[k], s);
  for (int k = 0; k < 256; k++) s = fmaf(A3[r * 256 + k], b2[k], s);
  be[r] = s;
}
__global__ __launch_bounds__(256) void k_q(const float* __restrict__ X,
                                           const float* __restrict__ We,
                                           const float* __restrict__ be,
                                           float* __restrict__ q) {
  int n = threadIdx.x & 63;
  int b = blockIdx.x * 4 + (threadIdx.x >> 6);
  const float* xr = X + (size_t)b * 2304;
  const float* wr = We + (size_t)n * 2304;
  float s = be[n];
  for (int k = 0; k < 2304; k++) s = fmaf(xr[k], wr[k], s);
  q[b * 64 + n] = s;
}

// ============================================================================
// Spatial attention + fc3. One wave per image. out3 NCHW fp32 [512][64][6][6].
// ============================================================================
__global__ __launch_bounds__(64) void k_attn(
    const float* __restrict__ out3, const float* __restrict__ q,
    const float* __restrict__ w3, const float* __restrict__ b3,
    float* __restrict__ out) {
  int b = blockIdx.x, t = threadIdx.x;
  __shared__ float ql[64], sc[36], gm[64];
  const float* o3 = out3 + (size_t)b * 2304;
  ql[t] = q[b * 64 + t];
  __syncthreads();
  float s = -INFINITY;
  if (t < 36) {
    float acc = 0.f;
    for (int c = 0; c < 64; c++) acc = fmaf(o3[c * 36 + t], ql[c], acc);
    s = acc;
  }
  float mx = s;
  for (int off = 32; off >= 1; off >>= 1) mx = fmaxf(mx, __shfl_xor(mx, off));
  float e = (t < 36) ? expf(s - mx) : 0.f;
  float sum = e;
  for (int off = 32; off >= 1; off >>= 1) sum += __shfl_xor(sum, off);
  if (t < 36) sc[t] = e / sum;
  __syncthreads();
  float gv = 0.f;
  for (int hw = 0; hw < 36; hw++) gv = fmaf(o3[t * 36 + hw], sc[hw], gv);
  gm[t] = gv;
  __syncthreads();
  if (t < 7) {
    float acc = b3[t];
    for (int c = 0; c < 64; c++) acc = fmaf(w3[t * 64 + c], gm[c], acc);
    out[b * 7 + t] = acc;
  }
}

// ============================================================================
extern "C" void kernel_launch(void* const* d_in, const int* in_sizes, int n_in,
                              void* d_out, int out_size, void* d_ws,
                              size_t ws_size, hipStream_t stream) {
  const float* x    = (const float*)d_in[0];
  const float* c1w  = (const float*)d_in[1];
  const float* c1b  = (const float*)d_in[2];
  const float* g1   = (const float*)d_in[3];
  const float* bb1  = (const float*)d_in[4];
  const float* m1   = (const float*)d_in[5];
  const float* v1   = (const float*)d_in[6];
  const float* c2w  = (const float*)d_in[7];
  const float* c2b  = (const float*)d_in[8];
  const float* g2   = (const float*)d_in[9];
  const float* bb2  = (const float*)d_in[10];
  const float* m2   = (const float*)d_in[11];
  const float* v2   = (const float*)d_in[12];
  const float* c3w  = (const float*)d_in[13];
  const float* c3b  = (const float*)d_in[14];
  const float* g3   = (const float*)d_in[15];
  const float* bb3  = (const float*)d_in[16];
  const float* m3   = (const float*)d_in[17];
  const float* v3   = (const float*)d_in[18];
  const float* fc1w = (const float*)d_in[19];
  const float* fc1b = (const float*)d_in[20];
  const float* fc2w = (const float*)d_in[21];
  const float* fc2b = (const float*)d_in[22];
  const float* attw = (const float*)d_in[23];
  const float* attb = (const float*)d_in[24];
  const float* fc3w = (const float*)d_in[25];
  const float* fc3b = (const float*)d_in[26];

  // chunking: per-chunk bf16 bufs out1p CH*173056 + out2p CH*25088 elems
  const size_t PER_CHUNK = (173056ULL + 25088ULL) * 2;  // bytes per image
  const size_t PERSIST = 4718592 + 589824 + 147456 + 131072 + 589824 + 256 +
                         131072 + 8192;  // out3+wt2+wt3+W32+We+be+q+align
  int CH = 512;
  while (CH > 8 && (size_t)CH * PER_CHUNK + PERSIST > ws_size) CH >>= 1;
  const int NCHK = 512 / CH;

  char* base = (char*)d_ws;
  size_t off = 0;
  auto alloc = [&](size_t nbytes) -> void* {
    void* p = base + off;
    off = (off + nbytes + 255) & ~(size_t)255;
    return p;
  };
  __hip_bfloat16* out1p = (__hip_bfloat16*)alloc((size_t)CH * 173056 * 2);
  __hip_bfloat16* out2p = (__hip_bfloat16*)alloc((size_t)CH * 25088 * 2);
  float* out3          = (float*)alloc(4718592);
  __hip_bfloat16* wt2  = (__hip_bfloat16*)alloc(589824);
  __hip_bfloat16* wt3  = (__hip_bfloat16*)alloc(147456);
  float* W32           = (float*)alloc(131072);
  float* We            = (float*)alloc(589824);
  float* be            = (float*)alloc(256);
  float* q             = (float*)alloc(131072);

  // weight prep + FC collapse
  k_twi<256, 128><<<1152, 256, 0, stream>>>(c2w, wt2);
  k_twi<128, 64><<<288, 256, 0, stream>>>(c3w, wt3);
  k_w32<<<128, 256, 0, stream>>>(attw, fc2w, W32);
  k_weff<<<576, 256, 0, stream>>>(W32, fc1w, We);
  k_beff<<<1, 64, 0, stream>>>(W32, fc1b, attw, fc2b, attb, be);

  for (int c = 0; c < NCHK; c++) {
    const float* xc = x + (size_t)c * CH * 2304;
    float* o3c = out3 + (size_t)c * CH * 2304;
    k_conv1<<<CH, 256, 0, stream>>>(xc, c1w, c1b, g1, bb1, m1, v1, out1p);
    k_halo2<<<CH, 256, 0, stream>>>(out2p);
    k_mconv<24, 256, 128, 2, 2, false>
        <<<CH * 6, 256, 0, stream>>>(out1p, wt2, c2b, g2, bb2, m2, v2, out2p);
    k_mconv<12, 128, 64, 1, 4, true>
        <<<CH * 3, 256, 0, stream>>>(out2p, wt3, c3b, g3, bb3, m3, v3, o3c);
  }

  k_q<<<128, 256, 0, stream>>>(out3, We, be, q);
  k_attn<<<512, 64, 0, stream>>>(out3, q, fc3w, fc3b, (float*)d_out);
}

// Round 5
// 537.015 us; speedup vs baseline: 5.8083x; 1.2361x over previous
//
#include <hip/hip_runtime.h>
#include <hip/hip_bf16.h>
#include <math.h>

#define EPS_BN 1e-5f

typedef __bf16 bf16x8 __attribute__((ext_vector_type(8)));
typedef float f32x4 __attribute__((ext_vector_type(4)));

// async global->LDS, 16B per lane. LDS dest must be wave-uniform base + lane*16.
__device__ __forceinline__ void gl2lds16(const void* g, void* l) {
  __builtin_amdgcn_global_load_lds(
      (const __attribute__((address_space(1))) unsigned int*)g,
      (__attribute__((address_space(3))) unsigned int*)l, 16, 0, 0);
}

// ============================================================================
// conv1 + bias + BN + ReLU + maxpool2: x[CH,1,48,48] fp32 ->
// out1p PADDED bf16 NHWC [CH][26][26][256] zero halo.
// Thread = channel. Sliding 4x4 window: 4 ds_read_b64 per output (broadcast),
// vs 16 b32 naive — conv1 is LDS-issue-bound.
// ============================================================================
__global__ __launch_bounds__(256) void k_conv1(
    const float* __restrict__ x, const float* __restrict__ w,
    const float* __restrict__ cb, const float* __restrict__ g,
    const float* __restrict__ bb, const float* __restrict__ m,
    const float* __restrict__ v, __hip_bfloat16* __restrict__ out1p) {
  __shared__ float xp[50 * 50];
  const int b = blockIdx.x;
  const int t = threadIdx.x;
  __hip_bfloat16* ob = out1p + (size_t)b * (26 * 26 * 256);
  const __hip_bfloat16 z = __float2bfloat16(0.f);
  for (int i = t; i < 26 * 256; i += 256) {
    ob[i] = z;
    ob[25 * 26 * 256 + i] = z;
  }
  for (int i = t; i < 24 * 2 * 256; i += 256) {
    int r = 1 + (i >> 9), side = (i >> 8) & 1, c = i & 255;
    ob[(r * 26 + side * 25) * 256 + c] = z;
  }
  for (int i = t; i < 2500; i += 256) xp[i] = 0.f;
  __syncthreads();
  const float* xb = x + (size_t)b * 2304;
  for (int i = t; i < 2304; i += 256) {
    int r = i / 48, c = i - r * 48;
    xp[(r + 1) * 50 + (c + 1)] = xb[i];
  }
  __syncthreads();
  float wr[9];
#pragma unroll
  for (int i = 0; i < 9; i++) wr[i] = w[t * 9 + i];
  const float scale = g[t] * rsqrtf(v[t] + EPS_BN);
  const float bias = (cb[t] - m[t]) * scale + bb[t];
  for (int oh = 0; oh < 24; oh++) {
    const int r0 = 2 * oh;
    float2 c01[4];
#pragma unroll
    for (int r = 0; r < 4; r++) c01[r] = *(const float2*)&xp[(r0 + r) * 50];
#pragma unroll 4
    for (int ow = 0; ow < 24; ow++) {
      float2 c23[4];
#pragma unroll
      for (int r = 0; r < 4; r++)
        c23[r] = *(const float2*)&xp[(r0 + r) * 50 + 2 * ow + 2];
      // window cols 2ow..2ow+3: [c01.x c01.y c23.x c23.y]
      float s4[4];
      int ii = 0;
#pragma unroll
      for (int dh = 0; dh < 2; dh++)
#pragma unroll
        for (int dw = 0; dw < 2; dw++, ii++) {
          float s = 0.f;
#pragma unroll
          for (int kh = 0; kh < 3; kh++) {
            const int rr = dh + kh;
            float col[4] = {c01[rr].x, c01[rr].y, c23[rr].x, c23[rr].y};
#pragma unroll
            for (int kw = 0; kw < 3; kw++)
              s = fmaf(col[dw + kw], wr[kh * 3 + kw], s);
          }
          s4[ii] = s * scale + bias;  // BN before pool (scale may be negative)
        }
      float mx = fmaxf(fmaxf(s4[0], s4[1]), fmaxf(s4[2], s4[3]));
      ob[((oh + 1) * 26 + (ow + 1)) * 256 + t] =
          __float2bfloat16(fmaxf(mx, 0.f));
#pragma unroll
      for (int r = 0; r < 4; r++) c01[r] = c23[r];
    }
  }
}

// ============================================================================
// Weight prep: w [OC][IC][3][3] fp32 -> bf16 interleaved [9][IC/8][OC][8]
// ============================================================================
template <int IC, int OC>
__global__ void k_twi(const float* __restrict__ w,
                      __hip_bfloat16* __restrict__ wt) {
  int idx = blockIdx.x * 256 + threadIdx.x;
  if (idx >= 9 * IC * OC) return;
  int icr = idx & 7;
  int oc = (idx >> 3) % OC;
  int rest = (idx >> 3) / OC;
  int icg = rest % (IC / 8);
  int p = rest / (IC / 8);
  int ic = icg * 8 + icr;
  wt[idx] = __float2bfloat16(w[(oc * IC + ic) * 9 + p]);
}

// zero the halo of padded out2p [CH][14][14][128] bf16 (conv2 writes interior)
__global__ void k_halo2(__hip_bfloat16* __restrict__ out2p) {
  int b = blockIdx.x, t = threadIdx.x;
  __hip_bfloat16* ob = out2p + (size_t)b * (14 * 14 * 128);
  const __hip_bfloat16 z = __float2bfloat16(0.f);
  for (int i = t; i < 14 * 128; i += 256) {
    ob[i] = z;
    ob[13 * 14 * 128 + i] = z;
  }
  for (int i = t; i < 12 * 2 * 128; i += 256) {
    int r = 1 + (i >> 8), side = (i >> 7) & 1, c = i & 127;
    ob[(r * 14 + side * 13) * 128 + c] = z;
  }
}

// ============================================================================
// MFMA implicit-GEMM conv + bias + BN + ReLU + fused maxpool2 (bf16, fp32 acc)
// in:  padded bf16 NHWC [nb][HP][HP][IC]  (HP = HW+2, zero halo)
// wt:  bf16 [9][IC/8][OC][8]
//
// A window: per kc-64 stage, the block's full 6-row padded input window lives
// in LDS; staged via global_load_lds (no VGPR roundtrip -> no spills), DOUBLE
// BUFFERED (prefetch stage s+1 before computing stage s; one barrier/stage).
// LDS layout linear for lane-contiguous DMA: 16B slot (r,c,kgslot) at
// (r*CP+c)*8 + kgslot, holding kg = kgslot ^ (c&7)  (xor swizzle => fragment
// reads hit all 8 bank groups, 2-way aliasing = free).
// B fragments per-lane direct from global (L2-resident; L1 absorbs wave-pair
// duplication).
// conv2: HW=24 IC=256 OC=128 waves 2x2 -> padded bf16 NHWC [14][14][128]
// conv3: HW=12 IC=128 OC=64  waves 1x4 -> fp32 NCHW [64][6][6]
// ============================================================================
template <int HW, int IC, int OC, int NW_M, int NW_N, bool NCHW_OUT>
__global__ __launch_bounds__(256) void k_mconv(
    const __hip_bfloat16* __restrict__ in, const __hip_bfloat16* __restrict__ wt,
    const float* __restrict__ cb, const float* __restrict__ gg,
    const float* __restrict__ bbv, const float* __restrict__ bm,
    const float* __restrict__ bv, void* __restrict__ outp) {
  constexpr int HP = HW + 2;
  constexpr int MT = NW_M * 48;        // block M rows
  constexpr int ROWS = MT / HW;        // output h-rows per block (4)
  constexpr int TILES = HW / ROWS;     // blocks per image
  constexpr int WN = OC / NW_N;        // wave N width
  constexpr int NF = WN / 16;          // n-frags per wave
  constexpr int CP = (HP + 15) & ~15;  // padded col count (32 / 16)
  constexpr int NCH = 6 * CP * 8;      // 16B slots per window
  constexpr int NLD = NCH / 256;       // DMA chunks per thread (6 / 3)
  constexpr int NSTG = IC / 64;        // kc stages (4 / 2)
  constexpr int ABUF = NCH * 16;       // bytes per window
  constexpr int ICG = IC / 8;
  constexpr int EPITCH = OC + 1;
  constexpr int EBYTES = 48 * EPITCH * 4;
  constexpr int SMB = (2 * ABUF) > EBYTES ? (2 * ABUF) : EBYTES;

  __shared__ __align__(16) char smraw[SMB];
  float* se = (float*)smraw;  // epilogue tile (aliases windows, dead by then)

  const int tid = threadIdx.x;
  const int wv = tid >> 6, ln = tid & 63;
  const int wm = (NW_M == 2) ? (wv >> 1) : 0;
  const int wn = (NW_M == 2) ? (wv & 1) : wv;
  const int lhi = ln >> 4, llo = ln & 15;

  const int b = blockIdx.x / TILES;
  const int T = blockIdx.x - b * TILES;
  const int h0 = T * ROWS;

  const __hip_bfloat16* inb = in + (size_t)b * HP * HP * IC;

  // staging source map: slot ci = tid + i*256 -> (r, c, kgslot), kg swizzled
  int srcoff[NLD];
#pragma unroll
  for (int i = 0; i < NLD; i++) {
    int ci = tid + i * 256;
    int kgslot = ci & 7;
    int rest = ci >> 3;
    int c = rest % CP;
    int r = rest / CP;
    int kg = kgslot ^ (c & 7);
    int sc = c < HP ? c : HP - 1;  // clamp pad cols (slots never read)
    srcoff[i] = ((h0 + r) * HP + sc) * IC + kg * 8;  // elements; +kc at use
  }
  // A-frag read precompute: spatial slot base & swizzle mask per (mt, pw)
  int spb[3][3], msk[3][3];
#pragma unroll
  for (int mt = 0; mt < 3; mt++) {
    int m = wm * 48 + mt * 16 + llo;
    int hl = m / HW, wl = m % HW;
#pragma unroll
    for (int pw = 0; pw < 3; pw++) {
      spb[mt][pw] = (hl * CP + wl + pw) * 8;
      msk[mt][pw] = (wl + pw) & 7;
    }
  }
  const __hip_bfloat16* wtb = wt + (size_t)(lhi * OC + wn * WN + llo) * 8;

  f32x4 acc[3][NF];
  const f32x4 fz = {0.f, 0.f, 0.f, 0.f};
#pragma unroll
  for (int i = 0; i < 3; i++)
#pragma unroll
    for (int j = 0; j < NF; j++) acc[i][j] = fz;

  // prologue: DMA stage 0 into window 0
#pragma unroll
  for (int i = 0; i < NLD; i++)
    gl2lds16(inb + srcoff[i], smraw + (tid + i * 256) * 16);
  __syncthreads();

#pragma unroll
  for (int s = 0; s < NSTG; s++) {
    if (s + 1 < NSTG) {  // prefetch next stage into other window
      char* nb = smraw + ((s + 1) & 1) * ABUF;
#pragma unroll
      for (int i = 0; i < NLD; i++)
        gl2lds16(inb + srcoff[i] + (s + 1) * 64, nb + (tid + i * 256) * 16);
    }
    const char* cw = smraw + (s & 1) * ABUF;
#pragma unroll
    for (int p = 0; p < 9; p++) {
      const int ph = p / 3, pw = p % 3;
#pragma unroll
      for (int ks = 0; ks < 2; ks++) {
        const int kg = ks * 4 + lhi;
        bf16x8 bf[NF];
#pragma unroll
        for (int j = 0; j < NF; j++)
          bf[j] = *(const bf16x8*)(wtb +
                                   ((size_t)(p * ICG + s * 8 + ks * 4) * OC) *
                                       8 +
                                   j * 128);
        bf16x8 af[3];
#pragma unroll
        for (int mt = 0; mt < 3; mt++) {
          int slot = spb[mt][pw] + ph * CP * 8 + (kg ^ msk[mt][pw]);
          af[mt] = *(const bf16x8*)(cw + slot * 16);
        }
#pragma unroll
        for (int mt = 0; mt < 3; mt++)
#pragma unroll
          for (int j = 0; j < NF; j++)
            acc[mt][j] = __builtin_amdgcn_mfma_f32_16x16x32_bf16(
                af[mt], bf[j], acc[mt][j], 0, 0, 0);
      }
    }
    __syncthreads();  // prefetch DMA drained; window s safe to overwrite
  }

  // ---- epilogue: per wm-pass: BN+ReLU -> E [48][EPITCH], 2x2 pool, store
  constexpr int PR = 48 / HW;  // h-rows per pass
  constexpr int POH = PR / 2;
  constexpr int OHW = HW / 2;
  constexpr int NP = POH * OHW * OC;
#pragma unroll
  for (int a = 0; a < NW_M; a++) {
    if (a) __syncthreads();  // (first pass already synced at loop exit)
    if (wm == a) {
#pragma unroll
      for (int j = 0; j < NF; j++) {
        int n = wn * WN + j * 16 + llo;
        float scale = gg[n] * rsqrtf(bv[n] + EPS_BN);
        float bias = (cb[n] - bm[n]) * scale + bbv[n];
#pragma unroll
        for (int mt = 0; mt < 3; mt++)
#pragma unroll
          for (int r = 0; r < 4; r++) {
            int mrow = mt * 16 + lhi * 4 + r;
            se[mrow * EPITCH + n] = fmaxf(acc[mt][j][r] * scale + bias, 0.f);
          }
      }
    }
    __syncthreads();
    for (int s = tid; s < NP; s += 256) {
      int n = s % OC;
      int ow = (s / OC) % OHW;
      int ohl = s / (OC * OHW);
      int mloc = (2 * ohl) * HW + 2 * ow;
      float x0 = se[mloc * EPITCH + n];
      float x1 = se[(mloc + 1) * EPITCH + n];
      float x2 = se[(mloc + HW) * EPITCH + n];
      float x3 = se[(mloc + HW + 1) * EPITCH + n];
      float mx = fmaxf(fmaxf(x0, x1), fmaxf(x2, x3));
      int oh = (h0 >> 1) + a * POH + ohl;
      if (NCHW_OUT) {
        ((float*)outp)[(((size_t)b * OC + n) * OHW + oh) * OHW + ow] = mx;
      } else {  // padded bf16 NHWC [OHW+2][OHW+2][OC], interior at +1
        ((__hip_bfloat16*)
             outp)[(((size_t)b * (OHW + 2) + oh + 1) * (OHW + 2) + ow + 1) *
                       OC +
                   n] = __float2bfloat16(mx);
      }
    }
    if (a + 1 < NW_M) __syncthreads();  // protect se before next pass writes
  }
}

// ============================================================================
// FC chain collapse (pure linear): W32 = att_w@fc2_w; W_eff = W32@fc1_w;
// b_eff = W32@fc1_b + att_w@fc2_b + att_b; q = out4 @ W_eff^T + b_eff
// ============================================================================
__global__ void k_w32(const float* __restrict__ A3, const float* __restrict__ A2,
                      float* __restrict__ W32) {
  int idx = blockIdx.x * 256 + threadIdx.x;  // 64*512
  int r = idx >> 9, c = idx & 511;
  float s = 0.f;
  for (int k = 0; k < 256; k++) s = fmaf(A3[r * 256 + k], A2[k * 512 + c], s);
  W32[idx] = s;
}
__global__ void k_weff(const float* __restrict__ W32, const float* __restrict__ A1,
                       float* __restrict__ We) {
  int idx = blockIdx.x * 256 + threadIdx.x;  // 64*2304
  int r = idx / 2304, c = idx - r * 2304;
  float s = 0.f;
  for (int k = 0; k < 512; k++) s = fmaf(W32[r * 512 + k], A1[k * 2304 + c], s);
  We[idx] = s;
}
__global__ void k_beff(const float* __restrict__ W32, const float* __restrict__ b1,
                       const float* __restrict__ A3, const float* __restrict__ b2,
                       const float* __restrict__ b3, float* __restrict__ be) {
  int r = threadIdx.x;  // 64
  float s = b3[r];
  for (int k = 0; k < 512; k++) s = fmaf(W32[r * 512 + k], b1[k], s);
  for (int k = 0; k < 256; k++) s = fmaf(A3[r * 256 + k], b2[k], s);
  be[r] = s;
}
__global__ __launch_bounds__(256) void k_q(const float* __restrict__ X,
                                           const float* __restrict__ We,
                                           const float* __restrict__ be,
                                           float* __restrict__ q) {
  int n = threadIdx.x & 63;
  int b = blockIdx.x * 4 + (threadIdx.x >> 6);
  const float* xr = X + (size_t)b * 2304;
  const float* wr = We + (size_t)n * 2304;
  float s = be[n];
  for (int k = 0; k < 2304; k++) s = fmaf(xr[k], wr[k], s);
  q[b * 64 + n] = s;
}

// ============================================================================
// Spatial attention + fc3. One wave per image. out3 NCHW fp32 [512][64][6][6].
// ============================================================================
__global__ __launch_bounds__(64) void k_attn(
    const float* __restrict__ out3, const float* __restrict__ q,
    const float* __restrict__ w3, const float* __restrict__ b3,
    float* __restrict__ out) {
  int b = blockIdx.x, t = threadIdx.x;
  __shared__ float ql[64], sc[36], gm[64];
  const float* o3 = out3 + (size_t)b * 2304;
  ql[t] = q[b * 64 + t];
  __syncthreads();
  float s = -INFINITY;
  if (t < 36) {
    float acc = 0.f;
    for (int c = 0; c < 64; c++) acc = fmaf(o3[c * 36 + t], ql[c], acc);
    s = acc;
  }
  float mx = s;
  for (int off = 32; off >= 1; off >>= 1) mx = fmaxf(mx, __shfl_xor(mx, off));
  float e = (t < 36) ? expf(s - mx) : 0.f;
  float sum = e;
  for (int off = 32; off >= 1; off >>= 1) sum += __shfl_xor(sum, off);
  if (t < 36) sc[t] = e / sum;
  __syncthreads();
  float gv = 0.f;
  for (int hw = 0; hw < 36; hw++) gv = fmaf(o3[t * 36 + hw], sc[hw], gv);
  gm[t] = gv;
  __syncthreads();
  if (t < 7) {
    float acc = b3[t];
    for (int c = 0; c < 64; c++) acc = fmaf(w3[t * 64 + c], gm[c], acc);
    out[b * 7 + t] = acc;
  }
}

// ============================================================================
extern "C" void kernel_launch(void* const* d_in, const int* in_sizes, int n_in,
                              void* d_out, int out_size, void* d_ws,
                              size_t ws_size, hipStream_t stream) {
  const float* x    = (const float*)d_in[0];
  const float* c1w  = (const float*)d_in[1];
  const float* c1b  = (const float*)d_in[2];
  const float* g1   = (const float*)d_in[3];
  const float* bb1  = (const float*)d_in[4];
  const float* m1   = (const float*)d_in[5];
  const float* v1   = (const float*)d_in[6];
  const float* c2w  = (const float*)d_in[7];
  const float* c2b  = (const float*)d_in[8];
  const float* g2   = (const float*)d_in[9];
  const float* bb2  = (const float*)d_in[10];
  const float* m2   = (const float*)d_in[11];
  const float* v2   = (const float*)d_in[12];
  const float* c3w  = (const float*)d_in[13];
  const float* c3b  = (const float*)d_in[14];
  const float* g3   = (const float*)d_in[15];
  const float* bb3  = (const float*)d_in[16];
  const float* m3   = (const float*)d_in[17];
  const float* v3   = (const float*)d_in[18];
  const float* fc1w = (const float*)d_in[19];
  const float* fc1b = (const float*)d_in[20];
  const float* fc2w = (const float*)d_in[21];
  const float* fc2b = (const float*)d_in[22];
  const float* attw = (const float*)d_in[23];
  const float* attb = (const float*)d_in[24];
  const float* fc3w = (const float*)d_in[25];
  const float* fc3b = (const float*)d_in[26];

  // chunking: per-chunk bf16 bufs out1p CH*173056 + out2p CH*25088 elems
  const size_t PER_CHUNK = (173056ULL + 25088ULL) * 2;  // bytes per image
  const size_t PERSIST = 4718592 + 589824 + 147456 + 131072 + 589824 + 256 +
                         131072 + 8192;  // out3+wt2+wt3+W32+We+be+q+align
  int CH = 512;
  while (CH > 8 && (size_t)CH * PER_CHUNK + PERSIST > ws_size) CH >>= 1;
  const int NCHK = 512 / CH;

  char* base = (char*)d_ws;
  size_t off = 0;
  auto alloc = [&](size_t nbytes) -> void* {
    void* p = base + off;
    off = (off + nbytes + 255) & ~(size_t)255;
    return p;
  };
  __hip_bfloat16* out1p = (__hip_bfloat16*)alloc((size_t)CH * 173056 * 2);
  __hip_bfloat16* out2p = (__hip_bfloat16*)alloc((size_t)CH * 25088 * 2);
  float* out3          = (float*)alloc(4718592);
  __hip_bfloat16* wt2  = (__hip_bfloat16*)alloc(589824);
  __hip_bfloat16* wt3  = (__hip_bfloat16*)alloc(147456);
  float* W32           = (float*)alloc(131072);
  float* We            = (float*)alloc(589824);
  float* be            = (float*)alloc(256);
  float* q             = (float*)alloc(131072);

  // weight prep + FC collapse
  k_twi<256, 128><<<1152, 256, 0, stream>>>(c2w, wt2);
  k_twi<128, 64><<<288, 256, 0, stream>>>(c3w, wt3);
  k_w32<<<128, 256, 0, stream>>>(attw, fc2w, W32);
  k_weff<<<576, 256, 0, stream>>>(W32, fc1w, We);
  k_beff<<<1, 64, 0, stream>>>(W32, fc1b, attw, fc2b, attb, be);

  for (int c = 0; c < NCHK; c++) {
    const float* xc = x + (size_t)c * CH * 2304;
    float* o3c = out3 + (size_t)c * CH * 2304;
    k_conv1<<<CH, 256, 0, stream>>>(xc, c1w, c1b, g1, bb1, m1, v1, out1p);
    k_halo2<<<CH, 256, 0, stream>>>(out2p);
    k_mconv<24, 256, 128, 2, 2, false>
        <<<CH * 6, 256, 0, stream>>>(out1p, wt2, c2b, g2, bb2, m2, v2, out2p);
    k_mconv<12, 128, 64, 1, 4, true>
        <<<CH * 3, 256, 0, stream>>>(out2p, wt3, c3b, g3, bb3, m3, v3, o3c);
  }

  k_q<<<128, 256, 0, stream>>>(out3, We, be, q);
  k_attn<<<512, 64, 0, stream>>>(out3, q, fc3w, fc3b, (float*)d_out);
}

// Round 6
// 493.868 us; speedup vs baseline: 6.3158x; 1.0874x over previous
//
#include <hip/hip_runtime.h>
#include <hip/hip_bf16.h>
#include <math.h>

#define EPS_BN 1e-5f

typedef __bf16 bf16x8 __attribute__((ext_vector_type(8)));
typedef float f32x4 __attribute__((ext_vector_type(4)));

// async global->LDS, 16B per lane. LDS dest must be wave-uniform base + lane*16
// (we pass base + tid*16 which matches lane-linear layout per wave).
__device__ __forceinline__ void gl2lds16(const void* g, void* l) {
  __builtin_amdgcn_global_load_lds(
      (const __attribute__((address_space(1))) unsigned int*)g,
      (__attribute__((address_space(3))) unsigned int*)l, 16, 0, 0);
}

// ============================================================================
// conv1 + bias + BN + ReLU + maxpool2: x[CH,1,48,48] fp32 ->
// out1p PADDED bf16 NHWC [CH][26][26][256] zero halo.
// One block per (image, 6-output-row band): 4x the blocks of the whole-image
// version -> 4 blocks/CU latency hiding. Thread = channel; sliding 4x4 window.
// ============================================================================
__global__ __launch_bounds__(256) void k_conv1(
    const float* __restrict__ x, const float* __restrict__ w,
    const float* __restrict__ cb, const float* __restrict__ g,
    const float* __restrict__ bb, const float* __restrict__ m,
    const float* __restrict__ v, __hip_bfloat16* __restrict__ out1p) {
  __shared__ float xp[14 * 50];
  const int bq = blockIdx.x;
  const int b = bq >> 2, q = bq & 3;  // band q: output rows 6q..6q+5
  const int t = threadIdx.x;
  __hip_bfloat16* ob = out1p + (size_t)b * (26 * 26 * 256);
  const __hip_bfloat16 z = __float2bfloat16(0.f);
  // halo zeroing split across bands
  if (q == 0)
    for (int i = t; i < 26 * 256; i += 256) ob[i] = z;
  if (q == 3)
    for (int i = t; i < 26 * 256; i += 256) ob[25 * 26 * 256 + i] = z;
  for (int i = t; i < 6 * 2 * 256; i += 256) {  // side cols of this band's rows
    int r = 1 + 6 * q + (i >> 9), side = (i >> 8) & 1, c = i & 255;
    ob[(r * 26 + side * 25) * 256 + c] = z;
  }
  for (int i = t; i < 14 * 50; i += 256) xp[i] = 0.f;
  __syncthreads();
  const float* xb = x + (size_t)b * 2304;
  for (int i = t; i < 14 * 48; i += 256) {
    int rr = i / 48, c = i - rr * 48;
    int gr = 12 * q - 1 + rr;  // global input row
    if (gr >= 0 && gr < 48) xp[rr * 50 + c + 1] = xb[gr * 48 + c];
  }
  __syncthreads();
  float wr[9];
#pragma unroll
  for (int i = 0; i < 9; i++) wr[i] = w[t * 9 + i];
  const float scale = g[t] * rsqrtf(v[t] + EPS_BN);
  const float bias = (cb[t] - m[t]) * scale + bb[t];
#pragma unroll
  for (int ohl = 0; ohl < 6; ohl++) {
    const int r0 = 2 * ohl;  // xp row of window top
    float2 c01[4];
#pragma unroll
    for (int r = 0; r < 4; r++) c01[r] = *(const float2*)&xp[(r0 + r) * 50];
#pragma unroll 4
    for (int ow = 0; ow < 24; ow++) {
      float2 c23[4];
#pragma unroll
      for (int r = 0; r < 4; r++)
        c23[r] = *(const float2*)&xp[(r0 + r) * 50 + 2 * ow + 2];
      float s4[4];
      int ii = 0;
#pragma unroll
      for (int dh = 0; dh < 2; dh++)
#pragma unroll
        for (int dw = 0; dw < 2; dw++, ii++) {
          float s = 0.f;
#pragma unroll
          for (int kh = 0; kh < 3; kh++) {
            const int rr = dh + kh;
            float col[4] = {c01[rr].x, c01[rr].y, c23[rr].x, c23[rr].y};
#pragma unroll
            for (int kw = 0; kw < 3; kw++)
              s = fmaf(col[dw + kw], wr[kh * 3 + kw], s);
          }
          s4[ii] = s * scale + bias;  // BN before pool (scale may be negative)
        }
      float mx = fmaxf(fmaxf(s4[0], s4[1]), fmaxf(s4[2], s4[3]));
      ob[((6 * q + ohl + 1) * 26 + (ow + 1)) * 256 + t] =
          __float2bfloat16(fmaxf(mx, 0.f));
#pragma unroll
      for (int r = 0; r < 4; r++) c01[r] = c23[r];
    }
  }
}

// ============================================================================
// Weight prep: w [OC][IC][3][3] fp32 -> bf16 interleaved [9][IC/8][OC][8]
// ============================================================================
template <int IC, int OC>
__global__ void k_twi(const float* __restrict__ w,
                      __hip_bfloat16* __restrict__ wt) {
  int idx = blockIdx.x * 256 + threadIdx.x;
  if (idx >= 9 * IC * OC) return;
  int icr = idx & 7;
  int oc = (idx >> 3) % OC;
  int rest = (idx >> 3) / OC;
  int icg = rest % (IC / 8);
  int p = rest / (IC / 8);
  int ic = icg * 8 + icr;
  wt[idx] = __float2bfloat16(w[(oc * IC + ic) * 9 + p]);
}

// zero the halo of padded out2p [CH][14][14][128] bf16 (conv2 writes interior)
__global__ void k_halo2(__hip_bfloat16* __restrict__ out2p) {
  int b = blockIdx.x, t = threadIdx.x;
  __hip_bfloat16* ob = out2p + (size_t)b * (14 * 14 * 128);
  const __hip_bfloat16 z = __float2bfloat16(0.f);
  for (int i = t; i < 14 * 128; i += 256) {
    ob[i] = z;
    ob[13 * 14 * 128 + i] = z;
  }
  for (int i = t; i < 12 * 2 * 128; i += 256) {
    int r = 1 + (i >> 8), side = (i >> 7) & 1, c = i & 127;
    ob[(r * 14 + side * 13) * 128 + c] = z;
  }
}

// ============================================================================
// MFMA implicit-GEMM conv + bias + BN + ReLU + fused maxpool2 (bf16, fp32 acc)
// in:  padded bf16 NHWC [nb][HP][HP][IC]  (HP = HW+2, zero halo)
// wt:  bf16 [9][IC/8][OC][8]
//
// A window in LDS via global_load_lds DMA, double-buffered, one barrier/stage.
// CP = HP exactly (no column padding): conv2 window = 1280 slots * 16B = 20KB,
// 2 windows = 40KB -> 4 blocks/CU (50% occupancy).  16B slot (r,c,kgslot) at
// (r*CP+c)*8 + kgslot holding kg = kgslot ^ (c&7) (xor swizzle: fragment reads
// spread over all 8 bank groups, <=2-way aliasing = free).
// B fragments per-lane direct from global (L2-resident weights).
// conv2: HW=24 IC=256 OC=128 waves 2x2 -> padded bf16 NHWC [14][14][128]
// conv3: HW=12 IC=128 OC=64  waves 1x4 -> fp32 NCHW [64][6][6]
// ============================================================================
template <int HW, int IC, int OC, int NW_M, int NW_N, bool NCHW_OUT>
__global__ __launch_bounds__(256) void k_mconv(
    const __hip_bfloat16* __restrict__ in, const __hip_bfloat16* __restrict__ wt,
    const float* __restrict__ cb, const float* __restrict__ gg,
    const float* __restrict__ bbv, const float* __restrict__ bm,
    const float* __restrict__ bv, void* __restrict__ outp) {
  constexpr int HP = HW + 2;
  constexpr int MT = NW_M * 48;     // block M rows
  constexpr int ROWS = MT / HW;     // output h-rows per block (4)
  constexpr int TILES = HW / ROWS;  // blocks per image
  constexpr int WN = OC / NW_N;     // wave N width
  constexpr int NF = WN / 16;       // n-frags per wave
  constexpr int CP = HP;            // exact column count (26 / 14)
  constexpr int NCH = 6 * CP * 8;   // real 16B slots per window (1248 / 672)
  constexpr int NCHP = (NCH + 255) & ~255;  // padded to DMA granularity
  constexpr int NLD = NCHP / 256;   // DMA chunks per thread (5 / 3)
  constexpr int NSTG = IC / 64;     // kc stages (4 / 2)
  constexpr int ABUF = NCHP * 16;   // bytes per window (20480 / 12288)
  constexpr int ICG = IC / 8;
  constexpr int EPITCH = OC + 1;
  constexpr int EBYTES = 48 * EPITCH * 4;
  constexpr int SMB = (2 * ABUF) > EBYTES ? (2 * ABUF) : EBYTES;

  __shared__ __align__(16) char smraw[SMB];
  float* se = (float*)smraw;  // epilogue tile (aliases windows, dead by then)

  const int tid = threadIdx.x;
  const int wv = tid >> 6, ln = tid & 63;
  const int wm = (NW_M == 2) ? (wv >> 1) : 0;
  const int wn = (NW_M == 2) ? (wv & 1) : wv;
  const int lhi = ln >> 4, llo = ln & 15;

  const int b = blockIdx.x / TILES;
  const int T = blockIdx.x - b * TILES;
  const int h0 = T * ROWS;

  const __hip_bfloat16* inb = in + (size_t)b * HP * HP * IC;

  // staging source map: slot ci = tid + i*256 -> (r, c, kgslot), kg swizzled
  int srcoff[NLD];
#pragma unroll
  for (int i = 0; i < NLD; i++) {
    int ci = tid + i * 256;
    if (ci >= NCH) ci = NCH - 1;  // pad slots: dup read, dest lands in pad
    int kgslot = ci & 7;
    int rest = ci >> 3;
    int c = rest % CP;
    int r = rest / CP;
    int kg = kgslot ^ (c & 7);
    srcoff[i] = ((h0 + r) * HP + c) * IC + kg * 8;  // elements; +kc at use
  }
  // A-frag read precompute: spatial slot base & swizzle mask per (mt, pw)
  int spb[3][3], msk[3][3];
#pragma unroll
  for (int mt = 0; mt < 3; mt++) {
    int m = wm * 48 + mt * 16 + llo;
    int hl = m / HW, wl = m % HW;
#pragma unroll
    for (int pw = 0; pw < 3; pw++) {
      spb[mt][pw] = (hl * CP + wl + pw) * 8;
      msk[mt][pw] = (wl + pw) & 7;
    }
  }
  const __hip_bfloat16* wtb = wt + (size_t)(lhi * OC + wn * WN + llo) * 8;

  f32x4 acc[3][NF];
  const f32x4 fz = {0.f, 0.f, 0.f, 0.f};
#pragma unroll
  for (int i = 0; i < 3; i++)
#pragma unroll
    for (int j = 0; j < NF; j++) acc[i][j] = fz;

  // prologue: DMA stage 0 into window 0
#pragma unroll
  for (int i = 0; i < NLD; i++)
    gl2lds16(inb + srcoff[i], smraw + (tid + i * 256) * 16);
  __syncthreads();

#pragma unroll
  for (int s = 0; s < NSTG; s++) {
    if (s + 1 < NSTG) {  // prefetch next stage into other window
      char* nb = smraw + ((s + 1) & 1) * ABUF;
#pragma unroll
      for (int i = 0; i < NLD; i++)
        gl2lds16(inb + srcoff[i] + (s + 1) * 64, nb + (tid + i * 256) * 16);
    }
    const char* cw = smraw + (s & 1) * ABUF;
#pragma unroll
    for (int p = 0; p < 9; p++) {
      const int ph = p / 3, pw = p % 3;
#pragma unroll
      for (int ks = 0; ks < 2; ks++) {
        const int kg = ks * 4 + lhi;
        bf16x8 bf[NF];
#pragma unroll
        for (int j = 0; j < NF; j++)
          bf[j] = *(const bf16x8*)(wtb +
                                   ((size_t)(p * ICG + s * 8 + ks * 4) * OC) *
                                       8 +
                                   j * 128);
        bf16x8 af[3];
#pragma unroll
        for (int mt = 0; mt < 3; mt++) {
          int slot = spb[mt][pw] + ph * CP * 8 + (kg ^ msk[mt][pw]);
          af[mt] = *(const bf16x8*)(cw + slot * 16);
        }
#pragma unroll
        for (int mt = 0; mt < 3; mt++)
#pragma unroll
          for (int j = 0; j < NF; j++)
            acc[mt][j] = __builtin_amdgcn_mfma_f32_16x16x32_bf16(
                af[mt], bf[j], acc[mt][j], 0, 0, 0);
      }
    }
    __syncthreads();  // prefetch DMA drained; window s safe to overwrite
  }

  // ---- epilogue: per wm-pass: BN+ReLU -> E [48][EPITCH], 2x2 pool, store
  constexpr int PR = 48 / HW;  // h-rows per pass
  constexpr int POH = PR / 2;
  constexpr int OHW = HW / 2;
  constexpr int NP = POH * OHW * OC;
#pragma unroll
  for (int a = 0; a < NW_M; a++) {
    if (a) __syncthreads();
    if (wm == a) {
#pragma unroll
      for (int j = 0; j < NF; j++) {
        int n = wn * WN + j * 16 + llo;
        float scale = gg[n] * rsqrtf(bv[n] + EPS_BN);
        float bias = (cb[n] - bm[n]) * scale + bbv[n];
#pragma unroll
        for (int mt = 0; mt < 3; mt++)
#pragma unroll
          for (int r = 0; r < 4; r++) {
            int mrow = mt * 16 + lhi * 4 + r;
            se[mrow * EPITCH + n] = fmaxf(acc[mt][j][r] * scale + bias, 0.f);
          }
      }
    }
    __syncthreads();
    for (int s = tid; s < NP; s += 256) {
      int n = s % OC;
      int ow = (s / OC) % OHW;
      int ohl = s / (OC * OHW);
      int mloc = (2 * ohl) * HW + 2 * ow;
      float x0 = se[mloc * EPITCH + n];
      float x1 = se[(mloc + 1) * EPITCH + n];
      float x2 = se[(mloc + HW) * EPITCH + n];
      float x3 = se[(mloc + HW + 1) * EPITCH + n];
      float mx = fmaxf(fmaxf(x0, x1), fmaxf(x2, x3));
      int oh = (h0 >> 1) + a * POH + ohl;
      if (NCHW_OUT) {
        ((float*)outp)[(((size_t)b * OC + n) * OHW + oh) * OHW + ow] = mx;
      } else {  // padded bf16 NHWC [OHW+2][OHW+2][OC], interior at +1
        ((__hip_bfloat16*)
             outp)[(((size_t)b * (OHW + 2) + oh + 1) * (OHW + 2) + ow + 1) *
                       OC +
                   n] = __float2bfloat16(mx);
      }
    }
    if (a + 1 < NW_M) __syncthreads();
  }
}

// ============================================================================
// FC chain collapse (pure linear): W32 = att_w@fc2_w; W_eff = W32@fc1_w
// (stored TRANSPOSED [2304][64] for coalesced k_q reads);
// b_eff = W32@fc1_b + att_w@fc2_b + att_b; q = out4 @ W_eff^T + b_eff
// ============================================================================
__global__ void k_w32(const float* __restrict__ A3, const float* __restrict__ A2,
                      float* __restrict__ W32) {
  int idx = blockIdx.x * 256 + threadIdx.x;  // 64*512
  int r = idx >> 9, c = idx & 511;
  float s = 0.f;
  for (int k = 0; k < 256; k++) s = fmaf(A3[r * 256 + k], A2[k * 512 + c], s);
  W32[idx] = s;
}
__global__ void k_weff(const float* __restrict__ W32, const float* __restrict__ A1,
                       float* __restrict__ Wet) {
  int idx = blockIdx.x * 256 + threadIdx.x;  // 64*2304
  int r = idx / 2304, c = idx - r * 2304;
  float s = 0.f;
  for (int k = 0; k < 512; k++) s = fmaf(W32[r * 512 + k], A1[k * 2304 + c], s);
  Wet[c * 64 + r] = s;  // transposed store
}
__global__ void k_beff(const float* __restrict__ W32, const float* __restrict__ b1,
                       const float* __restrict__ A3, const float* __restrict__ b2,
                       const float* __restrict__ b3, float* __restrict__ be) {
  int r = threadIdx.x;  // 64
  float s = b3[r];
  for (int k = 0; k < 512; k++) s = fmaf(W32[r * 512 + k], b1[k], s);
  for (int k = 0; k < 256; k++) s = fmaf(A3[r * 256 + k], b2[k], s);
  be[r] = s;
}
__global__ __launch_bounds__(256) void k_q(const float* __restrict__ X,
                                           const float* __restrict__ Wet,
                                           const float* __restrict__ be,
                                           float* __restrict__ q) {
  // block = 4 images x 64 outputs; X row wave-uniform (scalar-load eligible),
  // Wet row lane-consecutive (coalesced 256B per instruction)
  int n = threadIdx.x & 63;
  int b = blockIdx.x * 4 + (threadIdx.x >> 6);
  const float* xr = X + (size_t)b * 2304;
  float s = be[n];
  for (int k = 0; k < 2304; k++) s = fmaf(xr[k], Wet[k * 64 + n], s);
  q[b * 64 + n] = s;
}

// ============================================================================
// Spatial attention + fc3. One wave per image. out3 NCHW fp32 [512][64][6][6].
// ============================================================================
__global__ __launch_bounds__(64) void k_attn(
    const float* __restrict__ out3, const float* __restrict__ q,
    const float* __restrict__ w3, const float* __restrict__ b3,
    float* __restrict__ out) {
  int b = blockIdx.x, t = threadIdx.x;
  __shared__ float ql[64], sc[36], gm[64];
  const float* o3 = out3 + (size_t)b * 2304;
  ql[t] = q[b * 64 + t];
  __syncthreads();
  float s = -INFINITY;
  if (t < 36) {
    float acc = 0.f;
    for (int c = 0; c < 64; c++) acc = fmaf(o3[c * 36 + t], ql[c], acc);
    s = acc;
  }
  float mx = s;
  for (int off = 32; off >= 1; off >>= 1) mx = fmaxf(mx, __shfl_xor(mx, off));
  float e = (t < 36) ? expf(s - mx) : 0.f;
  float sum = e;
  for (int off = 32; off >= 1; off >>= 1) sum += __shfl_xor(sum, off);
  if (t < 36) sc[t] = e / sum;
  __syncthreads();
  float gv = 0.f;
  for (int hw = 0; hw < 36; hw++) gv = fmaf(o3[t * 36 + hw], sc[hw], gv);
  gm[t] = gv;
  __syncthreads();
  if (t < 7) {
    float acc = b3[t];
    for (int c = 0; c < 64; c++) acc = fmaf(w3[t * 64 + c], gm[c], acc);
    out[b * 7 + t] = acc;
  }
}

// ============================================================================
extern "C" void kernel_launch(void* const* d_in, const int* in_sizes, int n_in,
                              void* d_out, int out_size, void* d_ws,
                              size_t ws_size, hipStream_t stream) {
  const float* x    = (const float*)d_in[0];
  const float* c1w  = (const float*)d_in[1];
  const float* c1b  = (const float*)d_in[2];
  const float* g1   = (const float*)d_in[3];
  const float* bb1  = (const float*)d_in[4];
  const float* m1   = (const float*)d_in[5];
  const float* v1   = (const float*)d_in[6];
  const float* c2w  = (const float*)d_in[7];
  const float* c2b  = (const float*)d_in[8];
  const float* g2   = (const float*)d_in[9];
  const float* bb2  = (const float*)d_in[10];
  const float* m2   = (const float*)d_in[11];
  const float* v2   = (const float*)d_in[12];
  const float* c3w  = (const float*)d_in[13];
  const float* c3b  = (const float*)d_in[14];
  const float* g3   = (const float*)d_in[15];
  const float* bb3  = (const float*)d_in[16];
  const float* m3   = (const float*)d_in[17];
  const float* v3   = (const float*)d_in[18];
  const float* fc1w = (const float*)d_in[19];
  const float* fc1b = (const float*)d_in[20];
  const float* fc2w = (const float*)d_in[21];
  const float* fc2b = (const float*)d_in[22];
  const float* attw = (const float*)d_in[23];
  const float* attb = (const float*)d_in[24];
  const float* fc3w = (const float*)d_in[25];
  const float* fc3b = (const float*)d_in[26];

  // chunking: per-chunk bf16 bufs out1p CH*173056 + out2p CH*25088 elems
  const size_t PER_CHUNK = (173056ULL + 25088ULL) * 2;  // bytes per image
  const size_t PERSIST = 4718592 + 589824 + 147456 + 131072 + 589824 + 256 +
                         131072 + 8192;  // out3+wt2+wt3+W32+Wet+be+q+align
  int CH = 512;
  while (CH > 8 && (size_t)CH * PER_CHUNK + PERSIST > ws_size) CH >>= 1;
  const int NCHK = 512 / CH;

  char* base = (char*)d_ws;
  size_t off = 0;
  auto alloc = [&](size_t nbytes) -> void* {
    void* p = base + off;
    off = (off + nbytes + 255) & ~(size_t)255;
    return p;
  };
  __hip_bfloat16* out1p = (__hip_bfloat16*)alloc((size_t)CH * 173056 * 2);
  __hip_bfloat16* out2p = (__hip_bfloat16*)alloc((size_t)CH * 25088 * 2);
  float* out3          = (float*)alloc(4718592);
  __hip_bfloat16* wt2  = (__hip_bfloat16*)alloc(589824);
  __hip_bfloat16* wt3  = (__hip_bfloat16*)alloc(147456);
  float* W32           = (float*)alloc(131072);
  float* Wet           = (float*)alloc(589824);
  float* be            = (float*)alloc(256);
  float* q             = (float*)alloc(131072);

  // weight prep + FC collapse
  k_twi<256, 128><<<1152, 256, 0, stream>>>(c2w, wt2);
  k_twi<128, 64><<<288, 256, 0, stream>>>(c3w, wt3);
  k_w32<<<128, 256, 0, stream>>>(attw, fc2w, W32);
  k_weff<<<576, 256, 0, stream>>>(W32, fc1w, Wet);
  k_beff<<<1, 64, 0, stream>>>(W32, fc1b, attw, fc2b, attb, be);

  for (int c = 0; c < NCHK; c++) {
    const float* xc = x + (size_t)c * CH * 2304;
    float* o3c = out3 + (size_t)c * CH * 2304;
    k_conv1<<<CH * 4, 256, 0, stream>>>(xc, c1w, c1b, g1, bb1, m1, v1, out1p);
    k_halo2<<<CH, 256, 0, stream>>>(out2p);
    k_mconv<24, 256, 128, 2, 2, false>
        <<<CH * 6, 256, 0, stream>>>(out1p, wt2, c2b, g2, bb2, m2, v2, out2p);
    k_mconv<12, 128, 64, 1, 4, true>
        <<<CH * 3, 256, 0, stream>>>(out2p, wt3, c3b, g3, bb3, m3, v3, o3c);
  }

  k_q<<<128, 256, 0, stream>>>(out3, Wet, be, q);
  k_attn<<<512, 64, 0, stream>>>(out3, q, fc3w, fc3b, (float*)d_out);
}